// Round 9
// baseline (100.129 us; speedup 1.0000x reference)
//
#include <hip/hip_runtime.h>

// Le-ADMM reduction: state resets each iteration => output is one linear
// circular filter: out = crop_shift( IFFT2( K . FFT2(pad(x)) ) ),
// K = mu1[4]/((1+1e-6)*FH*FW) * conj(Hp) / (1e-6|Hp|^2 + 1e-5*PsiTPsi + 4e-5).
// Pairs packed z = x_a + i*x_b (K Hermitian => both results real).
//
// R8: TWIDDLE TABLES. R7 evidence: K4 at 44us under two different
// occupancy structures (4-blk dbuf / 8-blk in-place), VALUBusy ~52% both ->
// combined VALU+LDS issue saturation; only instruction removal helps.
// Twiddles are functions of (stage,p): precomputed by k_tw_init into a
// 54KB global table (L1/L2-hot), replacing per-item __sincosf (trans pipe)
// + 4-5 cmul power chains with 2-4 dwordx4 loads on the idle vmem pipe.
// Applied to ALL FFT kernels. Keeps: in-place K4 (18.4KB LDS, 8 blk/CU),
// pair-per-thread float4 LDS, XCD-chunked swizzle, zero-pad/crop fusion.

#define PI2 6.2831853071795864f

__device__ __forceinline__ float2 cadd(float2 a, float2 b){ return make_float2(a.x+b.x, a.y+b.y); }
__device__ __forceinline__ float2 csub(float2 a, float2 b){ return make_float2(a.x-b.x, a.y-b.y); }
__device__ __forceinline__ float2 cmul(float2 a, float2 b){ return make_float2(a.x*b.x - a.y*b.y, a.x*b.y + a.y*b.x); }
__device__ __forceinline__ float4 pk(float2 a, float2 b){ return make_float4(a.x,a.y,b.x,b.y); }

// Row kernels: pad +1 per 16 (b64 access).
__device__ __forceinline__ int IDX(int a){ return a + (a >> 4); }
#define IDXSZ(n) ((n) + ((n) >> 4))
// Column kernels: pad +2 per 32 (keeps even->even so float4 stays aligned).
__device__ __forceinline__ int IDXP(int a){ return a + ((a >> 5) << 1); }
#define IDXPSZ(n) ((n) + (((n) >> 5) << 1) + 4)

// Pair load/store: both columns at per-col position pos.
__device__ __forceinline__ void ldp(const float2* __restrict__ b, int pos,
                                    float2& v0, float2& v1){
    const float4 t = *(const float4*)&b[IDXP(2*pos)];
    v0 = make_float2(t.x,t.y); v1 = make_float2(t.z,t.w);
}
__device__ __forceinline__ void stp(float2* __restrict__ b, int pos,
                                    float2 v0, float2 v1){
    *(float4*)&b[IDXP(2*pos)] = pk(v0, v1);
}

// ---- twiddle tables (global, built by k_tw_init each launch) ----
// Layout in float2 units; 6-stride tables: [p][6]={w1..w5,pad};
// 8-stride: [p][8]={w1..w7,pad}; 4-stride: [p][4]={w1..w4}.
#define TW_CS1   0      // col s1   fwd: 180p, ncur 1080  (6-stride)
#define TW_CM2   1080   // col mid2 fwd: 30p,  ncur 180
#define TW_CM3   1260   // col mid3 fwd: 5p,   ncur 30
#define TW_CF    1290   // col fused inv: 216p, ncur 1080 (4-stride)
#define TW_CM5   2154   // col mid5 inv: 36p,  ncur 216
#define TW_CM6   2370   // col mid6 inv: 6p,   ncur 36
#define TW_RS1F  2406   // row s1   fwd: 240p, ncur 1920  (8-stride)
#define TW_RM2F  4326   // row mid2 fwd: 30p,  ncur 240
#define TW_RM3F  4566   // row mid3 fwd: 5p,   ncur 30    (6-stride)
#define TW_RS1I  4596   // row s1   inv
#define TW_RM2I  6516   // row mid2 inv
#define TW_RM3I  6756   // row mid3 inv
#define TW_TOTAL 6786

__device__ __forceinline__ void ldw5(const float2* __restrict__ t, int p, float2 w[5]){
    const float4* q = (const float4*)(t + p*6);
    float4 a = q[0], b = q[1]; float2 c = *(const float2*)(q + 2);
    w[0]=make_float2(a.x,a.y); w[1]=make_float2(a.z,a.w);
    w[2]=make_float2(b.x,b.y); w[3]=make_float2(b.z,b.w); w[4]=c;
}
__device__ __forceinline__ void ldw7(const float2* __restrict__ t, int p, float2 w[7]){
    const float4* q = (const float4*)(t + p*8);
    float4 a = q[0], b = q[1], c = q[2]; float2 d = *(const float2*)(q + 3);
    w[0]=make_float2(a.x,a.y); w[1]=make_float2(a.z,a.w);
    w[2]=make_float2(b.x,b.y); w[3]=make_float2(b.z,b.w);
    w[4]=make_float2(c.x,c.y); w[5]=make_float2(c.z,c.w); w[6]=d;
}
__device__ __forceinline__ void ldw4(const float2* __restrict__ t, int p, float2 w[4]){
    const float4* q = (const float4*)(t + p*4);
    float4 a = q[0], b = q[1];
    w[0]=make_float2(a.x,a.y); w[1]=make_float2(a.z,a.w);
    w[2]=make_float2(b.x,b.y); w[3]=make_float2(b.z,b.w);
}

__global__ __launch_bounds__(256) void k_tw_init(float2* __restrict__ TW)
{
    // segments: {off, ep, np, ncur, dir}
    const int seg[12][5] = {
        {TW_CS1, 6,5,1080,-1}, {TW_CM2, 6,5, 180,-1}, {TW_CM3, 6,5,  30,-1},
        {TW_CF,  4,4,1080, 1}, {TW_CM5, 6,5, 216, 1}, {TW_CM6, 6,5,  36, 1},
        {TW_RS1F,8,7,1920,-1}, {TW_RM2F,8,7, 240,-1}, {TW_RM3F,6,5,  30,-1},
        {TW_RS1I,8,7,1920, 1}, {TW_RM2I,8,7, 240, 1}, {TW_RM3I,6,5,  30, 1},
    };
    for (int i = blockIdx.x*256 + threadIdx.x; i < TW_TOTAL; i += gridDim.x*256) {
        int s = 0;
        #pragma unroll
        for (int k = 1; k < 12; ++k) if (i >= seg[k][0]) s = k;
        const int l = i - seg[s][0];
        const int ep = seg[s][1], np = seg[s][2], ncur = seg[s][3], dir = seg[s][4];
        const int p = l / ep, u = l - p*ep;
        float2 w = make_float2(1.f, 0.f);
        if (u < np) {
            const int e = (p*(u+1)) % ncur;
            float sv, cv;
            sincosf((float)dir * PI2 * (float)e / (float)ncur, &sv, &cv);
            w = make_float2(cv, sv);
        }
        TW[i] = w;
    }
}

template<int DIR>
__device__ __forceinline__ void dft3(float2 x0, float2 x1, float2 x2,
                                     float2& y0, float2& y1, float2& y2)
{
    constexpr float s3 = (float)DIR * 0.8660254037844386f;
    float2 t = cadd(x1, x2), u = csub(x1, x2);
    float2 m = make_float2(x0.x - 0.5f*t.x, x0.y - 0.5f*t.y);
    float2 iu = make_float2(-s3*u.y, s3*u.x);
    y0 = cadd(x0, t); y1 = cadd(m, iu); y2 = csub(m, iu);
}

template<int DIR>
__device__ __forceinline__ void dft4(float2 a0, float2 a1, float2 a2, float2 a3,
                                     float2& b0, float2& b1, float2& b2, float2& b3)
{
    float2 t0 = cadd(a0,a2), t1 = csub(a0,a2), t2 = cadd(a1,a3), t3 = csub(a1,a3);
    float2 j3 = make_float2(-(float)DIR*t3.y, (float)DIR*t3.x);
    b0 = cadd(t0,t2); b2 = csub(t0,t2); b1 = cadd(t1,j3); b3 = csub(t1,j3);
}

template<int DIR>
__device__ __forceinline__ void dft6(const float2 a[6], float2 b[6])
{
    float2 e0,e1,e2,o0,o1,o2;
    dft3<DIR>(a[0],a[2],a[4], e0,e1,e2);
    dft3<DIR>(a[1],a[3],a[5], o0,o1,o2);
    constexpr float s3 = (float)DIR * 0.8660254037844386f;
    float2 w1 = make_float2( 0.5f, s3);
    float2 w2 = make_float2(-0.5f, s3);
    float2 t1 = cmul(w1,o1), t2 = cmul(w2,o2);
    b[0]=cadd(e0,o0); b[3]=csub(e0,o0);
    b[1]=cadd(e1,t1); b[4]=csub(e1,t1);
    b[2]=cadd(e2,t2); b[5]=csub(e2,t2);
}

template<int DIR>
__device__ __forceinline__ void dft8(const float2 a[8], float2 b[8])
{
    float2 e0,e1,e2,e3,o0,o1,o2,o3;
    dft4<DIR>(a[0],a[2],a[4],a[6], e0,e1,e2,e3);
    dft4<DIR>(a[1],a[3],a[5],a[7], o0,o1,o2,o3);
    constexpr float c = 0.70710678118654752f;
    float2 w1 = make_float2( c, (float)DIR*c);
    float2 w3 = make_float2(-c, (float)DIR*c);
    float2 t1 = cmul(w1,o1);
    float2 t2 = make_float2(-(float)DIR*o2.y, (float)DIR*o2.x);
    float2 t3 = cmul(w3,o3);
    b[0]=cadd(e0,o0); b[4]=csub(e0,o0);
    b[1]=cadd(e1,t1); b[5]=csub(e1,t1);
    b[2]=cadd(e2,t2); b[6]=csub(e2,t2);
    b[3]=cadd(e3,t3); b[7]=csub(e3,t3);
}

template<int DIR>
__device__ __forceinline__ void dft5(const float2 a[5], float2 b[5])
{
    constexpr float C1 = 0.30901699437494742f, S1c = 0.9510565162951535f;
    constexpr float C2 = -0.8090169943749475f, S2c = 0.5877852522924731f;
    float2 t1 = cadd(a[1],a[4]), t2 = cadd(a[2],a[3]), d1 = csub(a[1],a[4]), d2 = csub(a[2],a[3]);
    float2 m1 = make_float2(a[0].x + C1*t1.x + C2*t2.x, a[0].y + C1*t1.y + C2*t2.y);
    float2 m2 = make_float2(a[0].x + C2*t1.x + C1*t2.x, a[0].y + C2*t1.y + C1*t2.y);
    float2 e1 = make_float2(S1c*d1.x + S2c*d2.x, S1c*d1.y + S2c*d2.y);
    float2 e2 = make_float2(S2c*d1.x - S1c*d2.x, S2c*d1.y - S1c*d2.y);
    float2 ie1 = make_float2(-(float)DIR*e1.y, (float)DIR*e1.x);
    float2 ie2 = make_float2(-(float)DIR*e2.y, (float)DIR*e2.x);
    b[0] = make_float2(a[0].x + t1.x + t2.x, a[0].y + t1.y + t2.y);
    b[1] = cadd(m1, ie1); b[4] = csub(m1, ie1);
    b[2] = cadd(m2, ie2); b[3] = csub(m2, ie2);
}

// Generic middle Stockham stage (rows; R = 6 or 8), LDS -> LDS, b64 slots.
template<int DIR, int R, int NCUR, int S>
__device__ __forceinline__ void mid_stage(const float2* __restrict__ src,
                                          float2* __restrict__ dst,
                                          const float2* __restrict__ tw, int tid)
{
    constexpr int M  = NCUR / R;
    constexpr int NB = M * S;
    for (int i = tid; i < NB; i += 256) {
        const int p = i / S;
        float2 a[R], b[R];
        #pragma unroll
        for (int t = 0; t < R; ++t) a[t] = src[IDX(i + S*M*t)];
        if constexpr (R == 6) dft6<DIR>(a,b); else dft8<DIR>(a,b);
        if constexpr (R == 8) {
            float2 w[7]; ldw7(tw, p, w);
            #pragma unroll
            for (int u = 1; u < 8; ++u) b[u] = cmul(b[u], w[u-1]);
        } else {
            float2 w[5]; ldw5(tw, p, w);
            #pragma unroll
            for (int u = 1; u < 6; ++u) b[u] = cmul(b[u], w[u-1]);
        }
        const int ob = (i - p*S) + S*(R*p);
        #pragma unroll
        for (int u = 0; u < R; ++u) dst[IDX(ob + S*u)] = b[u];
    }
}

// Column middle stage (K2 path, dbuf), pair-per-thread (R=6).
template<int DIR, int NCUR, int SC>
__device__ __forceinline__ void mid_pair(const float2* __restrict__ src,
                                         float2* __restrict__ dst,
                                         const float2* __restrict__ tw, int tid)
{
    constexpr int NB = 180;
    for (int ic = tid; ic < NB; ic += 256) {
        const int p = ic / SC;
        float2 a0[6], a1[6], b0[6], b1[6];
        #pragma unroll
        for (int t = 0; t < 6; ++t) ldp(src, ic + NB*t, a0[t], a1[t]);
        dft6<DIR>(a0,b0); dft6<DIR>(a1,b1);
        float2 w[5]; ldw5(tw, p, w);
        #pragma unroll
        for (int u = 1; u < 6; ++u){ b0[u]=cmul(b0[u],w[u-1]); b1[u]=cmul(b1[u],w[u-1]); }
        const int ob = (ic - p*SC) + SC*6*p;
        #pragma unroll
        for (int u = 0; u < 6; ++u) stp(dst, ob + SC*u, b0[u], b1[u]);
    }
}

// Column middle stage IN-PLACE (K4 path): read-all -> barrier -> write-all
// -> barrier. 180 items, one per thread (uniform barriers).
template<int DIR, int NCUR, int SC>
__device__ __forceinline__ void mid_pair_ip(float2* __restrict__ buf,
                                            const float2* __restrict__ tw, int tid)
{
    constexpr int NB = 180;
    const bool act = tid < NB;
    float2 b0[6], b1[6]; int ob = 0;
    if (act) {
        const int p = tid / SC;
        float2 a0[6], a1[6];
        #pragma unroll
        for (int t = 0; t < 6; ++t) ldp(buf, tid + NB*t, a0[t], a1[t]);
        dft6<DIR>(a0,b0); dft6<DIR>(a1,b1);
        float2 w[5]; ldw5(tw, p, w);
        #pragma unroll
        for (int u = 1; u < 6; ++u){ b0[u]=cmul(b0[u],w[u-1]); b1[u]=cmul(b1[u],w[u-1]); }
        ob = (tid - p*SC) + SC*6*p;
    }
    __syncthreads();
    if (act) {
        #pragma unroll
        for (int u = 0; u < 6; ++u) stp(buf, ob + SC*u, b0[u], b1[u]);
    }
    __syncthreads();
}

// Column stage 1 (radix-6, SC=1, DIR=-1) from global, pair-per-thread,
// zero-pad: padded rows 270..809 nonzero. Writes only (fresh buffer).
__device__ __forceinline__ void col_s1_fwd_pair(const float2* __restrict__ g, int c0,
                                                float2* __restrict__ bA,
                                                const float2* __restrict__ tw, int tid)
{
    const float2 z = make_float2(0.f,0.f);
    const float4* gc = (const float4*)(g + c0);
    for (int p = tid; p < 180; p += 256) {
        float2 a0[6], a1[6], b0[6], b1[6];
        a0[0]=a0[5]=a1[0]=a1[5]=z;
        if (p >= 90) { float4 t = gc[(p-90)*960]; a0[1]=make_float2(t.x,t.y); a1[1]=make_float2(t.z,t.w); }
        else         { a0[1]=a1[1]=z; }
        { float4 t = gc[(p+90)*960];  a0[2]=make_float2(t.x,t.y); a1[2]=make_float2(t.z,t.w); }
        { float4 t = gc[(p+270)*960]; a0[3]=make_float2(t.x,t.y); a1[3]=make_float2(t.z,t.w); }
        if (p < 90)  { float4 t = gc[(p+450)*960]; a0[4]=make_float2(t.x,t.y); a1[4]=make_float2(t.z,t.w); }
        else         { a0[4]=a1[4]=z; }
        dft6<-1>(a0,b0); dft6<-1>(a1,b1);
        float2 w[5]; ldw5(tw, p, w);
        #pragma unroll
        for (int u = 1; u < 6; ++u){ b0[u]=cmul(b0[u],w[u-1]); b1[u]=cmul(b1[u],w[u-1]); }
        #pragma unroll
        for (int u = 0; u < 6; ++u) stp(bA, 6*p + u, b0[u], b1[u]);
    }
}

// Fused center IN-PLACE: fwd-final radix-5 (twiddle-free; spectrum k=i+216u)
// -> *K -> inverse-first radix-5 (table twiddle) -> scatter to colpos 5p+u.
__device__ __forceinline__ void fused5K5_ip(float2* __restrict__ buf,
                                            const float4* __restrict__ KI,
                                            const float2* __restrict__ tw,
                                            int cpair, int tid)
{
    const float4* Kc = KI + cpair*1080;
    const bool act = tid < 216;
    float2 d0[5], d1[5];
    if (act) {
        float2 a0[5],a1[5],s0[5],s1[5];
        #pragma unroll
        for (int u = 0; u < 5; ++u) ldp(buf, tid + 216*u, a0[u], a1[u]);
        dft5<-1>(a0,s0); dft5<-1>(a1,s1);
        #pragma unroll
        for (int u = 0; u < 5; ++u) {
            float4 kk = Kc[tid + 216*u];
            s0[u] = cmul(s0[u], make_float2(kk.x,kk.y));
            s1[u] = cmul(s1[u], make_float2(kk.z,kk.w));
        }
        dft5<1>(s0,d0); dft5<1>(s1,d1);
        float2 w[4]; ldw4(tw, tid, w);
        #pragma unroll
        for (int u = 1; u < 5; ++u){ d0[u]=cmul(d0[u],w[u-1]); d1[u]=cmul(d1[u],w[u-1]); }
    }
    __syncthreads();
    if (act) {
        #pragma unroll
        for (int u = 0; u < 5; ++u) stp(buf, 5*tid + u, d0[u], d1[u]);
    }
    __syncthreads();
}

// Inverse final radix-6 (SC=180, p=0, twiddle-free) fused with crop.
__device__ __forceinline__ void fin6_crop_pair(const float2* __restrict__ src,
                                               float2* __restrict__ Zp,
                                               int c0, int tid)
{
    float4* gc = (float4*)(Zp + c0);
    for (int m = tid; m < 180; m += 256) {
        float2 a0[6],a1[6],b0[6],b1[6];
        #pragma unroll
        for (int t = 0; t < 6; ++t) ldp(src, m + 180*t, a0[t], a1[t]);
        dft6<1>(a0,b0); dft6<1>(a1,b1);
        gc[(m+270)*960] = pk(b0[0], b1[0]);
        if (m < 90)  gc[(m+450)*960] = pk(b0[1], b1[1]);
        if (m >= 90) gc[(m-90)*960]  = pk(b0[4], b1[4]);
        gc[(m+90)*960]  = pk(b0[5], b1[5]);
    }
}

// ---------------- row (1920 = 8*8*6*5) pieces ----------------

template<bool HASB>
__device__ __forceinline__ void row_s1_fwd(const float* __restrict__ xa,
                                           const float* __restrict__ xb,
                                           float2* __restrict__ bA,
                                           const float2* __restrict__ tw, int tid)
{
    const float2 z = make_float2(0.f,0.f);
    for (int p = tid; p < 240; p += 256) {
        float2 a[8], b[8];
        a[0]=z; a[1]=z; a[6]=z; a[7]=z;
        a[2] = make_float2(xa[p],     HASB ? xb[p]     : 0.f);
        a[3] = make_float2(xa[p+240], HASB ? xb[p+240] : 0.f);
        a[4] = make_float2(xa[p+480], HASB ? xb[p+480] : 0.f);
        a[5] = make_float2(xa[p+720], HASB ? xb[p+720] : 0.f);
        dft8<-1>(a,b);
        float2 w[7]; ldw7(tw, p, w);
        #pragma unroll
        for (int u = 1; u < 8; ++u) b[u] = cmul(b[u], w[u-1]);
        #pragma unroll
        for (int u = 0; u < 8; ++u) bA[IDX(8*p + u)] = b[u];
    }
}

__device__ __forceinline__ void row_s1_inv(const float2* __restrict__ Zp,
                                           float2* __restrict__ bA,
                                           const float2* __restrict__ tw, int tid)
{
    for (int p = tid; p < 240; p += 256) {
        float2 a[8], b[8];
        #pragma unroll
        for (int t = 0; t < 8; ++t) a[t] = Zp[p + 240*t];
        dft8<1>(a,b);
        float2 w[7]; ldw7(tw, p, w);
        #pragma unroll
        for (int u = 1; u < 8; ++u) b[u] = cmul(b[u], w[u-1]);
        #pragma unroll
        for (int u = 0; u < 8; ++u) bA[IDX(8*p + u)] = b[u];
    }
}

template<int DIR>
__device__ __forceinline__ void row_fin5_store(const float2* __restrict__ src,
                                               float2* __restrict__ gdst, int tid)
{
    for (int q = tid; q < 384; q += 256) {
        float2 a[5], b[5];
        #pragma unroll
        for (int u = 0; u < 5; ++u) a[u] = src[IDX(q + 384*u)];
        dft5<DIR>(a,b);
        #pragma unroll
        for (int u = 0; u < 5; ++u) gdst[q + 384*u] = b[u];
    }
}

// ---------------- kernels ----------------

// K1: row FFTs of padded h. Hrow[r][k], r=0..539 = padded row 270+r.
__global__ __launch_bounds__(256,5) void k_row_fft_h(const float* __restrict__ h,
                                                     float2* __restrict__ Hrow,
                                                     const float2* __restrict__ TW)
{
    __shared__ float2 bA[IDXSZ(1920)], bB[IDXSZ(1920)];
    const int tid = threadIdx.x, r = blockIdx.x;
    row_s1_fwd<false>(h + r*960, nullptr, bA, TW+TW_RS1F, tid); __syncthreads();
    mid_stage<-1,8,240, 8>(bA, bB, TW+TW_RM2F, tid); __syncthreads();
    mid_stage<-1,6, 30,64>(bB, bA, TW+TW_RM3F, tid); __syncthreads();
    row_fin5_store<-1>(bA, Hrow + r*1920, tid);
}

// K2: column FFTs of Hrow (pair/thread, dbuf) + build pair-interleaved KI.
__global__ __launch_bounds__(256,4) void k_col_fft_h_buildK(const float2* __restrict__ Hrow,
                                                            const float* __restrict__ mu1,
                                                            float4* __restrict__ KI,
                                                            const float2* __restrict__ TW)
{
    __shared__ float2 bA[IDXPSZ(2160)], bB[IDXPSZ(2160)];
    const int tid = threadIdx.x;
    const int xcd = blockIdx.x & 7, idx = blockIdx.x >> 3;
    const int cpair = xcd*120 + idx, c0 = cpair*2;
    col_s1_fwd_pair(Hrow, c0, bA, TW+TW_CS1, tid);  __syncthreads();
    mid_pair<-1,180, 6>(bA, bB, TW+TW_CM2, tid);    __syncthreads();
    mid_pair<-1, 30,36>(bB, bA, TW+TW_CM3, tid);    __syncthreads();
    const float sc = mu1[4] / ((1.0f + 1e-6f) * 2073600.0f);
    const float cos0 = __cosf(PI2 * (float)(c0  ) * (1.0f/1920.0f));
    const float cos1 = __cosf(PI2 * (float)(c0+1) * (1.0f/1920.0f));
    float4* Kc = KI + cpair*1080;
    for (int p = tid; p < 216; p += 256) {
        float2 a0[5],a1[5],b0[5],b1[5];
        #pragma unroll
        for (int u = 0; u < 5; ++u) ldp(bA, p + 216*u, a0[u], a1[u]);
        dft5<-1>(a0,b0); dft5<-1>(a1,b1);
        #pragma unroll
        for (int u = 0; u < 5; ++u) {
            const int k = p + 216*u;
            const float cosk = __cosf(PI2 * (float)k * (1.0f/1080.0f));
            float m0 = b0[u].x*b0[u].x + b0[u].y*b0[u].y;
            float m1 = b1[u].x*b1[u].x + b1[u].y*b1[u].y;
            float f0 = sc / (1e-6f*m0 + 1e-5f*(4.0f - 2.0f*cosk - 2.0f*cos0) + 4e-5f);
            float f1 = sc / (1e-6f*m1 + 1e-5f*(4.0f - 2.0f*cosk - 2.0f*cos1) + 4e-5f);
            Kc[k] = make_float4(f0*b0[u].x, -f0*b0[u].y, f1*b1[u].x, -f1*b1[u].y);
        }
    }
}

// K3: row FFTs of padded x, pairs packed z = x_a + i*x_b.
__global__ __launch_bounds__(256,5) void k_row_fft_x(const float* __restrict__ x,
                                                     float2* __restrict__ Z,
                                                     const float2* __restrict__ TW)
{
    __shared__ float2 bA[IDXSZ(1920)], bB[IDXSZ(1920)];
    const int tid = threadIdx.x;
    const int p = blockIdx.x / 540;
    const int r = blockIdx.x % 540;
    row_s1_fwd<true>(x + ((2*p)*540 + r)*960, x + ((2*p+1)*540 + r)*960,
                     bA, TW+TW_RS1F, tid);
    __syncthreads();
    mid_stage<-1,8,240, 8>(bA, bB, TW+TW_RM2F, tid); __syncthreads();
    mid_stage<-1,6, 30,64>(bB, bA, TW+TW_RM3F, tid); __syncthreads();
    row_fin5_store<-1>(bA, Z + (p*540 + r)*1920, tid);
}

// K4: fused column pass, IN-PLACE single LDS buffer (18.4KB, 8 blocks/CU).
// s1(6,global) -> mid6 -> mid6 -> fused5K5 -> mid6 -> mid6 -> fin6+crop.
// XCD-chunked swizzle: xcd = bid&7, idx = bid>>3 in [0,480).
__global__ __launch_bounds__(256,8) void k_col_fused(float2* __restrict__ Z,
                                                     const float4* __restrict__ KI,
                                                     const float2* __restrict__ TW)
{
    __shared__ float2 buf[IDXPSZ(2160)];
    const int tid = threadIdx.x;
    const int xcd = blockIdx.x & 7, idx = blockIdx.x >> 3;
    const int pp  = idx / 120;
    const int cpair = xcd*120 + (idx - pp*120), c0 = cpair*2;
    float2* Zp = Z + pp*540*1920;
    col_s1_fwd_pair(Zp, c0, buf, TW+TW_CS1, tid);  __syncthreads();
    mid_pair_ip<-1,180, 6>(buf, TW+TW_CM2, tid);
    mid_pair_ip<-1, 30,36>(buf, TW+TW_CM3, tid);
    fused5K5_ip(buf, KI, TW+TW_CF, cpair, tid);
    mid_pair_ip< 1,216, 5>(buf, TW+TW_CM5, tid);
    mid_pair_ip< 1, 36,30>(buf, TW+TW_CM6, tid);
    fin6_crop_pair(buf, Zp, c0, tid);
}

// K5: row IFFTs + column crop remap + split pair into two real outputs.
__global__ __launch_bounds__(256,5) void k_row_ifft_out(const float2* __restrict__ Z,
                                                        float* __restrict__ out,
                                                        const float2* __restrict__ TW)
{
    __shared__ float2 bA[IDXSZ(1920)], bB[IDXSZ(1920)];
    const int tid = threadIdx.x;
    const int p = blockIdx.x / 540;
    const int r = blockIdx.x % 540;
    row_s1_inv(Z + (p*540 + r)*1920, bA, TW+TW_RS1I, tid); __syncthreads();
    mid_stage<1,8,240, 8>(bA, bB, TW+TW_RM2I, tid); __syncthreads();
    mid_stage<1,6, 30,64>(bB, bA, TW+TW_RM3I, tid); __syncthreads();
    float* oa = out + ((2*p)*540 + r)*960;
    float* ob = out + ((2*p+1)*540 + r)*960;
    for (int q = tid; q < 384; q += 256) {
        float2 a[5], b[5];
        #pragma unroll
        for (int u = 0; u < 5; ++u) a[u] = bA[IDX(q + 384*u)];
        dft5<1>(a,b);
        oa[q+480] = b[0].x; ob[q+480] = b[0].y;
        if (q < 96)   { oa[q+864] = b[1].x; ob[q+864] = b[1].y; }
        if (q >= 288) { oa[q-288] = b[3].x; ob[q-288] = b[3].y; }
        oa[q+96]  = b[4].x; ob[q+96]  = b[4].y;
    }
}

extern "C" void kernel_launch(void* const* d_in, const int* in_sizes, int n_in,
                              void* d_out, int out_size, void* d_ws, size_t ws_size,
                              hipStream_t stream)
{
    (void)in_sizes; (void)n_in; (void)out_size; (void)ws_size;
    const float* x   = (const float*)d_in[0];
    const float* h   = (const float*)d_in[1];
    const float* mu1 = (const float*)d_in[2];
    float*       out = (float*)d_out;

    // ws layout: TW (8192 f2 = 64KB) | KI (960*1080 f4 = 16.6MB) |
    // Z (4*540*1920 c64 = 33.2MB); Hrow aliases Z.
    float2* TW   = (float2*)d_ws;
    float4* KI   = (float4*)(TW + 8192);
    float2* Z    = (float2*)(KI + 960*1080);
    float2* Hrow = Z;

    k_tw_init         <<<27,     256, 0, stream>>>(TW);
    k_row_fft_h       <<<540,    256, 0, stream>>>(h, Hrow, TW);
    k_col_fft_h_buildK<<<960,    256, 0, stream>>>(Hrow, mu1, KI, TW);
    k_row_fft_x       <<<4*540,  256, 0, stream>>>(x, Z, TW);
    k_col_fused       <<<3840,   256, 0, stream>>>(Z, KI, TW);
    k_row_ifft_out    <<<4*540,  256, 0, stream>>>(Z, out, TW);
}

// Round 10
// 84.370 us; speedup vs baseline: 1.1868x; 1.1868x over previous
//
#include <hip/hip_runtime.h>

// Le-ADMM reduction: state resets each iteration => output is one linear
// circular filter: out = crop_shift( IFFT2( K . FFT2(pad(x)) ) ),
// K = mu1[4]/((1+1e-6)*FH*FW) * conj(Hp) / (1e-6|Hp|^2 + 1e-5*PsiTPsi + 4e-5).
// Pairs packed z = x_a + i*x_b (K Hermitian => both results real).
//
// R9: (a) R8 twiddle tables REVERTED (vmem latency on the barrier-fenced
// critical path beat sincos on the idle trans pipe: K4 44->55us). K4/K2
// restored to R7 (sincos, K4 in-place 18.4KB / 8 blk/CU).
// (b) ROW kernels paired (2 rows of one plane per block): float4 LDS,
// single in-place 32.6KB buffer, shared sincos+twiddle chain per butterfly
// pair -- the same +20% technique R5 proved on columns. Passes have
// 240/320/384 items -> 1-2 items/thread uniform read-all/barrier/write-all.
// (c) K1 (h rows) merged into the row-fwd kernel (blocks >= 1080, old
// single-row path on the same LDS); 4 launches total; Hrow separate region.

#define PI2 6.2831853071795864f

__device__ __forceinline__ float2 cadd(float2 a, float2 b){ return make_float2(a.x+b.x, a.y+b.y); }
__device__ __forceinline__ float2 csub(float2 a, float2 b){ return make_float2(a.x-b.x, a.y-b.y); }
__device__ __forceinline__ float2 cmul(float2 a, float2 b){ return make_float2(a.x*b.x - a.y*b.y, a.x*b.y + a.y*b.x); }
__device__ __forceinline__ float4 pk(float2 a, float2 b){ return make_float4(a.x,a.y,b.x,b.y); }

// b64 pad (h single-row path): +1 f2 per 16.
__device__ __forceinline__ int IDX(int a){ return a + (a >> 4); }
#define IDXSZ(n) ((n) + ((n) >> 4))
// Column-kernel f2 pad: +2 per 32 (float4-aligned).
__device__ __forceinline__ int IDXP(int a){ return a + ((a >> 5) << 1); }
#define IDXPSZ(n) ((n) + (((n) >> 5) << 1) + 4)
// Row-pair float4 slot pad: +1 slot per 16 (breaks stride-8-slot patterns
// to 8 lanes per 4-bank set = the b128 BW floor).
__device__ __forceinline__ int IDX4(int a){ return a + (a >> 4); }
#define IDX4SZ(n) ((n) + ((n) >> 4) + 2)

// Col-pair LDS load/store (f2 buffer, float4 access).
__device__ __forceinline__ void ldp(const float2* __restrict__ b, int pos,
                                    float2& v0, float2& v1){
    const float4 t = *(const float4*)&b[IDXP(2*pos)];
    v0 = make_float2(t.x,t.y); v1 = make_float2(t.z,t.w);
}
__device__ __forceinline__ void stp(float2* __restrict__ b, int pos,
                                    float2 v0, float2 v1){
    *(float4*)&b[IDXP(2*pos)] = pk(v0, v1);
}
// Row-pair LDS (float4 buffer).
__device__ __forceinline__ void ld4(const float4* __restrict__ b, int pos,
                                    float2& v0, float2& v1){
    const float4 t = b[IDX4(pos)];
    v0 = make_float2(t.x,t.y); v1 = make_float2(t.z,t.w);
}
__device__ __forceinline__ void st4(float4* __restrict__ b, int pos,
                                    float2 v0, float2 v1){
    b[IDX4(pos)] = pk(v0, v1);
}

template<int DIR>
__device__ __forceinline__ void dft3(float2 x0, float2 x1, float2 x2,
                                     float2& y0, float2& y1, float2& y2)
{
    constexpr float s3 = (float)DIR * 0.8660254037844386f;
    float2 t = cadd(x1, x2), u = csub(x1, x2);
    float2 m = make_float2(x0.x - 0.5f*t.x, x0.y - 0.5f*t.y);
    float2 iu = make_float2(-s3*u.y, s3*u.x);
    y0 = cadd(x0, t); y1 = cadd(m, iu); y2 = csub(m, iu);
}

template<int DIR>
__device__ __forceinline__ void dft4(float2 a0, float2 a1, float2 a2, float2 a3,
                                     float2& b0, float2& b1, float2& b2, float2& b3)
{
    float2 t0 = cadd(a0,a2), t1 = csub(a0,a2), t2 = cadd(a1,a3), t3 = csub(a1,a3);
    float2 j3 = make_float2(-(float)DIR*t3.y, (float)DIR*t3.x);
    b0 = cadd(t0,t2); b2 = csub(t0,t2); b1 = cadd(t1,j3); b3 = csub(t1,j3);
}

template<int DIR>
__device__ __forceinline__ void dft6(const float2 a[6], float2 b[6])
{
    float2 e0,e1,e2,o0,o1,o2;
    dft3<DIR>(a[0],a[2],a[4], e0,e1,e2);
    dft3<DIR>(a[1],a[3],a[5], o0,o1,o2);
    constexpr float s3 = (float)DIR * 0.8660254037844386f;
    float2 w1 = make_float2( 0.5f, s3);
    float2 w2 = make_float2(-0.5f, s3);
    float2 t1 = cmul(w1,o1), t2 = cmul(w2,o2);
    b[0]=cadd(e0,o0); b[3]=csub(e0,o0);
    b[1]=cadd(e1,t1); b[4]=csub(e1,t1);
    b[2]=cadd(e2,t2); b[5]=csub(e2,t2);
}

template<int DIR>
__device__ __forceinline__ void dft8(const float2 a[8], float2 b[8])
{
    float2 e0,e1,e2,e3,o0,o1,o2,o3;
    dft4<DIR>(a[0],a[2],a[4],a[6], e0,e1,e2,e3);
    dft4<DIR>(a[1],a[3],a[5],a[7], o0,o1,o2,o3);
    constexpr float c = 0.70710678118654752f;
    float2 w1 = make_float2( c, (float)DIR*c);
    float2 w3 = make_float2(-c, (float)DIR*c);
    float2 t1 = cmul(w1,o1);
    float2 t2 = make_float2(-(float)DIR*o2.y, (float)DIR*o2.x);
    float2 t3 = cmul(w3,o3);
    b[0]=cadd(e0,o0); b[4]=csub(e0,o0);
    b[1]=cadd(e1,t1); b[5]=csub(e1,t1);
    b[2]=cadd(e2,t2); b[6]=csub(e2,t2);
    b[3]=cadd(e3,t3); b[7]=csub(e3,t3);
}

template<int DIR>
__device__ __forceinline__ void dft5(const float2 a[5], float2 b[5])
{
    constexpr float C1 = 0.30901699437494742f, S1c = 0.9510565162951535f;
    constexpr float C2 = -0.8090169943749475f, S2c = 0.5877852522924731f;
    float2 t1 = cadd(a[1],a[4]), t2 = cadd(a[2],a[3]), d1 = csub(a[1],a[4]), d2 = csub(a[2],a[3]);
    float2 m1 = make_float2(a[0].x + C1*t1.x + C2*t2.x, a[0].y + C1*t1.y + C2*t2.y);
    float2 m2 = make_float2(a[0].x + C2*t1.x + C1*t2.x, a[0].y + C2*t1.y + C1*t2.y);
    float2 e1 = make_float2(S1c*d1.x + S2c*d2.x, S1c*d1.y + S2c*d2.y);
    float2 e2 = make_float2(S2c*d1.x - S1c*d2.x, S2c*d1.y - S1c*d2.y);
    float2 ie1 = make_float2(-(float)DIR*e1.y, (float)DIR*e1.x);
    float2 ie2 = make_float2(-(float)DIR*e2.y, (float)DIR*e2.x);
    b[0] = make_float2(a[0].x + t1.x + t2.x, a[0].y + t1.y + t2.y);
    b[1] = cadd(m1, ie1); b[4] = csub(m1, ie1);
    b[2] = cadd(m2, ie2); b[3] = csub(m2, ie2);
}

// ============ h single-row path (b64, dbuf) ============

__device__ __forceinline__ void row_s1_fwd_h(const float* __restrict__ xa,
                                             float2* __restrict__ bA, int tid)
{
    constexpr float STEP = -PI2 / 1920.0f;
    const float2 z = make_float2(0.f,0.f);
    for (int p = tid; p < 240; p += 256) {
        float2 a[8], b[8];
        a[0]=z; a[1]=z; a[6]=z; a[7]=z;
        a[2] = make_float2(xa[p],     0.f);
        a[3] = make_float2(xa[p+240], 0.f);
        a[4] = make_float2(xa[p+480], 0.f);
        a[5] = make_float2(xa[p+720], 0.f);
        dft8<-1>(a,b);
        float sv, cv; __sincosf(STEP * (float)p, &sv, &cv);
        float2 w1 = make_float2(cv, sv), w = w1;
        b[1] = cmul(b[1], w);
        #pragma unroll
        for (int u = 2; u < 8; ++u) { w = cmul(w, w1); b[u] = cmul(b[u], w); }
        #pragma unroll
        for (int u = 0; u < 8; ++u) bA[IDX(8*p + u)] = b[u];
    }
}

template<int DIR, int R, int NCUR, int S>
__device__ __forceinline__ void mid_stage(const float2* __restrict__ src,
                                          float2* __restrict__ dst, int tid)
{
    constexpr int M  = NCUR / R;
    constexpr int NB = M * S;
    constexpr float STEP = (float)DIR * PI2 / (float)NCUR;
    for (int i = tid; i < NB; i += 256) {
        const int p = i / S;
        float2 a[R], b[R];
        #pragma unroll
        for (int t = 0; t < R; ++t) a[t] = src[IDX(i + S*M*t)];
        if constexpr (R == 6) dft6<DIR>(a,b); else dft8<DIR>(a,b);
        float sv, cv; __sincosf(STEP * (float)p, &sv, &cv);
        float2 w1 = make_float2(cv, sv), w = w1;
        b[1] = cmul(b[1], w);
        #pragma unroll
        for (int u = 2; u < R; ++u) { w = cmul(w, w1); b[u] = cmul(b[u], w); }
        const int ob = (i - p*S) + S*(R*p);
        #pragma unroll
        for (int u = 0; u < R; ++u) dst[IDX(ob + S*u)] = b[u];
    }
}

__device__ __forceinline__ void row_fin5_store_h(const float2* __restrict__ src,
                                                 float2* __restrict__ gdst, int tid)
{
    for (int q = tid; q < 384; q += 256) {
        float2 a[5], b[5];
        #pragma unroll
        for (int u = 0; u < 5; ++u) a[u] = src[IDX(q + 384*u)];
        dft5<-1>(a,b);
        #pragma unroll
        for (int u = 0; u < 5; ++u) gdst[q + 384*u] = b[u];
    }
}

// ============ row-pair path (float4, in-place) ============
// Slot s holds {row0.re,row0.im,row1.re,row1.im} at per-row position s.

// s1 fwd (radix-8, S=1), zero-pad a[2..5] nonzero; writes only.
__device__ __forceinline__ void rp_s1_fwd(const float* __restrict__ xa,
                                          const float* __restrict__ xb,
                                          float4* __restrict__ sb, int tid)
{
    constexpr float STEP = -PI2 / 1920.0f;
    const float2 z = make_float2(0.f,0.f);
    for (int p = tid; p < 240; p += 256) {
        float2 a0[8], a1[8], b0[8], b1[8];
        a0[0]=a0[1]=a0[6]=a0[7]=z; a1[0]=a1[1]=a1[6]=a1[7]=z;
        #pragma unroll
        for (int t = 0; t < 4; ++t) {
            a0[2+t] = make_float2(xa[p+240*t],     xb[p+240*t]);
            a1[2+t] = make_float2(xa[960+p+240*t], xb[960+p+240*t]);
        }
        dft8<-1>(a0,b0); dft8<-1>(a1,b1);
        float sv, cv; __sincosf(STEP*(float)p, &sv, &cv);
        float2 w1 = make_float2(cv,sv), w = w1;
        b0[1]=cmul(b0[1],w); b1[1]=cmul(b1[1],w);
        #pragma unroll
        for (int u = 2; u < 8; ++u){ w = cmul(w,w1); b0[u]=cmul(b0[u],w); b1[u]=cmul(b1[u],w); }
        #pragma unroll
        for (int u = 0; u < 8; ++u) st4(sb, 8*p+u, b0[u], b1[u]);
    }
}

// s1 inv (radix-8, S=1), full read from two spectrum rows; writes only.
__device__ __forceinline__ void rp_s1_inv(const float2* __restrict__ Zr0,
                                          const float2* __restrict__ Zr1,
                                          float4* __restrict__ sb, int tid)
{
    constexpr float STEP = PI2 / 1920.0f;
    for (int p = tid; p < 240; p += 256) {
        float2 a0[8], a1[8], b0[8], b1[8];
        #pragma unroll
        for (int t = 0; t < 8; ++t) { a0[t] = Zr0[p+240*t]; a1[t] = Zr1[p+240*t]; }
        dft8<1>(a0,b0); dft8<1>(a1,b1);
        float sv, cv; __sincosf(STEP*(float)p, &sv, &cv);
        float2 w1 = make_float2(cv,sv), w = w1;
        b0[1]=cmul(b0[1],w); b1[1]=cmul(b1[1],w);
        #pragma unroll
        for (int u = 2; u < 8; ++u){ w = cmul(w,w1); b0[u]=cmul(b0[u],w); b1[u]=cmul(b1[u],w); }
        #pragma unroll
        for (int u = 0; u < 8; ++u) st4(sb, 8*p+u, b0[u], b1[u]);
    }
}

// mid radix-8 (NCUR=240, S=8): 240 items, 1/thread, in-place.
template<int DIR>
__device__ __forceinline__ void rp_mid8_ip(float4* __restrict__ sb, int tid)
{
    constexpr float STEP = (float)DIR * PI2 / 240.0f;
    const bool act = tid < 240;
    float2 b0[8], b1[8]; int ob = 0;
    if (act) {
        const int p = tid >> 3;
        float2 a0[8], a1[8];
        #pragma unroll
        for (int t = 0; t < 8; ++t) ld4(sb, tid + 240*t, a0[t], a1[t]);
        dft8<DIR>(a0,b0); dft8<DIR>(a1,b1);
        float sv, cv; __sincosf(STEP*(float)p, &sv, &cv);
        float2 w1 = make_float2(cv,sv), w = w1;
        b0[1]=cmul(b0[1],w); b1[1]=cmul(b1[1],w);
        #pragma unroll
        for (int u = 2; u < 8; ++u){ w = cmul(w,w1); b0[u]=cmul(b0[u],w); b1[u]=cmul(b1[u],w); }
        ob = (tid - 8*p) + 64*p;
    }
    __syncthreads();
    if (act) {
        #pragma unroll
        for (int u = 0; u < 8; ++u) st4(sb, ob + 8*u, b0[u], b1[u]);
    }
    __syncthreads();
}

// mid radix-6 (NCUR=30, S=64): 320 items -> item0=tid (all), item1=256+tid
// (tid<64, p=4 const). In-place.
template<int DIR>
__device__ __forceinline__ void rp_mid6_ip(float4* __restrict__ sb, int tid)
{
    constexpr float STEP = (float)DIR * PI2 / 30.0f;
    float2 c0[6], c1[6], d0[6], d1[6]; int ob0, ob1 = 0;
    {
        const int i = tid, p = i >> 6;
        float2 a0[6], a1[6];
        #pragma unroll
        for (int t = 0; t < 6; ++t) ld4(sb, i + 320*t, a0[t], a1[t]);
        dft6<DIR>(a0,c0); dft6<DIR>(a1,c1);
        float sv, cv; __sincosf(STEP*(float)p, &sv, &cv);
        float2 w1 = make_float2(cv,sv), w = w1;
        c0[1]=cmul(c0[1],w); c1[1]=cmul(c1[1],w);
        #pragma unroll
        for (int u = 2; u < 6; ++u){ w = cmul(w,w1); c0[u]=cmul(c0[u],w); c1[u]=cmul(c1[u],w); }
        ob0 = (i - 64*p) + 384*p;
    }
    const bool act2 = tid < 64;
    if (act2) {
        const int i = 256 + tid;                 // p = 4
        float2 a0[6], a1[6];
        #pragma unroll
        for (int t = 0; t < 6; ++t) ld4(sb, i + 320*t, a0[t], a1[t]);
        dft6<DIR>(a0,d0); dft6<DIR>(a1,d1);
        float sv, cv; __sincosf(STEP*4.0f, &sv, &cv);
        float2 w1 = make_float2(cv,sv), w = w1;
        d0[1]=cmul(d0[1],w); d1[1]=cmul(d1[1],w);
        #pragma unroll
        for (int u = 2; u < 6; ++u){ w = cmul(w,w1); d0[u]=cmul(d0[u],w); d1[u]=cmul(d1[u],w); }
        ob1 = tid + 1536;
    }
    __syncthreads();
    {
        #pragma unroll
        for (int u = 0; u < 6; ++u) st4(sb, ob0 + 64*u, c0[u], c1[u]);
    }
    if (act2) {
        #pragma unroll
        for (int u = 0; u < 6; ++u) st4(sb, ob1 + 64*u, d0[u], d1[u]);
    }
    __syncthreads();
}

// fin radix-5 fwd (p=0, twiddle-free), read LDS -> write 2 spectrum rows.
__device__ __forceinline__ void rp_fin5_storeZ(const float4* __restrict__ sb,
                                               float2* __restrict__ Zr0,
                                               float2* __restrict__ Zr1, int tid)
{
    for (int q = tid; q < 384; q += 256) {
        float2 a0[5],a1[5],b0[5],b1[5];
        #pragma unroll
        for (int u = 0; u < 5; ++u) ld4(sb, q + 384*u, a0[u], a1[u]);
        dft5<-1>(a0,b0); dft5<-1>(a1,b1);
        #pragma unroll
        for (int u = 0; u < 5; ++u) { Zr0[q+384*u] = b0[u]; Zr1[q+384*u] = b1[u]; }
    }
}

// fin radix-5 inv + crop ((j+1440)%1920) + split pair into 2 real images,
// for both rows: u=0 -> j=q+480; u=1 (q<96) -> j=q+864; u=3 (q>=288) ->
// j=q-288; u=4 -> j=q+96.
__device__ __forceinline__ void rp_fin5_crop(const float4* __restrict__ sb,
                                             float* __restrict__ oa0, float* __restrict__ ob0,
                                             float* __restrict__ oa1, float* __restrict__ ob1,
                                             int tid)
{
    for (int q = tid; q < 384; q += 256) {
        float2 a0[5],a1[5],b0[5],b1[5];
        #pragma unroll
        for (int u = 0; u < 5; ++u) ld4(sb, q + 384*u, a0[u], a1[u]);
        dft5<1>(a0,b0); dft5<1>(a1,b1);
        oa0[q+480] = b0[0].x; ob0[q+480] = b0[0].y;
        oa1[q+480] = b1[0].x; ob1[q+480] = b1[0].y;
        if (q < 96)   { oa0[q+864] = b0[1].x; ob0[q+864] = b0[1].y;
                        oa1[q+864] = b1[1].x; ob1[q+864] = b1[1].y; }
        if (q >= 288) { oa0[q-288] = b0[3].x; ob0[q-288] = b0[3].y;
                        oa1[q-288] = b1[3].x; ob1[q-288] = b1[3].y; }
        oa0[q+96]  = b0[4].x; ob0[q+96]  = b0[4].y;
        oa1[q+96]  = b1[4].x; ob1[q+96]  = b1[4].y;
    }
}

// ============ column path (R7: sincos, pair-per-thread) ============

__device__ __forceinline__ void col_s1_fwd_pair(const float2* __restrict__ g, int c0,
                                                float2* __restrict__ bA, int tid)
{
    constexpr float STEP = -PI2 / 1080.0f;
    const float2 z = make_float2(0.f,0.f);
    const float4* gc = (const float4*)(g + c0);
    for (int p = tid; p < 180; p += 256) {
        float2 a0[6], a1[6], b0[6], b1[6];
        a0[0]=a0[5]=a1[0]=a1[5]=z;
        if (p >= 90) { float4 t = gc[(p-90)*960]; a0[1]=make_float2(t.x,t.y); a1[1]=make_float2(t.z,t.w); }
        else         { a0[1]=a1[1]=z; }
        { float4 t = gc[(p+90)*960];  a0[2]=make_float2(t.x,t.y); a1[2]=make_float2(t.z,t.w); }
        { float4 t = gc[(p+270)*960]; a0[3]=make_float2(t.x,t.y); a1[3]=make_float2(t.z,t.w); }
        if (p < 90)  { float4 t = gc[(p+450)*960]; a0[4]=make_float2(t.x,t.y); a1[4]=make_float2(t.z,t.w); }
        else         { a0[4]=a1[4]=z; }
        dft6<-1>(a0,b0); dft6<-1>(a1,b1);
        float sv, cv; __sincosf(STEP*(float)p, &sv, &cv);
        float2 w1 = make_float2(cv,sv), w = w1;
        b0[1]=cmul(b0[1],w); b1[1]=cmul(b1[1],w);
        #pragma unroll
        for (int u = 2; u < 6; ++u){ w = cmul(w,w1); b0[u]=cmul(b0[u],w); b1[u]=cmul(b1[u],w); }
        #pragma unroll
        for (int u = 0; u < 6; ++u) stp(bA, 6*p + u, b0[u], b1[u]);
    }
}

template<int DIR, int NCUR, int SC>
__device__ __forceinline__ void mid_pair(const float2* __restrict__ src,
                                         float2* __restrict__ dst, int tid)
{
    constexpr int NB = 180;
    constexpr float STEP = (float)DIR * PI2 / (float)NCUR;
    for (int ic = tid; ic < NB; ic += 256) {
        const int p = ic / SC;
        float2 a0[6], a1[6], b0[6], b1[6];
        #pragma unroll
        for (int t = 0; t < 6; ++t) ldp(src, ic + NB*t, a0[t], a1[t]);
        dft6<DIR>(a0,b0); dft6<DIR>(a1,b1);
        float sv, cv; __sincosf(STEP*(float)p, &sv, &cv);
        float2 w1 = make_float2(cv,sv), w = w1;
        b0[1]=cmul(b0[1],w); b1[1]=cmul(b1[1],w);
        #pragma unroll
        for (int u = 2; u < 6; ++u){ w = cmul(w,w1); b0[u]=cmul(b0[u],w); b1[u]=cmul(b1[u],w); }
        const int ob = (ic - p*SC) + SC*6*p;
        #pragma unroll
        for (int u = 0; u < 6; ++u) stp(dst, ob + SC*u, b0[u], b1[u]);
    }
}

template<int DIR, int NCUR, int SC>
__device__ __forceinline__ void mid_pair_ip(float2* __restrict__ buf, int tid)
{
    constexpr int NB = 180;
    constexpr float STEP = (float)DIR * PI2 / (float)NCUR;
    const bool act = tid < NB;
    float2 b0[6], b1[6]; int ob = 0;
    if (act) {
        const int p = tid / SC;
        float2 a0[6], a1[6];
        #pragma unroll
        for (int t = 0; t < 6; ++t) ldp(buf, tid + NB*t, a0[t], a1[t]);
        dft6<DIR>(a0,b0); dft6<DIR>(a1,b1);
        float sv, cv; __sincosf(STEP*(float)p, &sv, &cv);
        float2 w1 = make_float2(cv,sv), w = w1;
        b0[1]=cmul(b0[1],w); b1[1]=cmul(b1[1],w);
        #pragma unroll
        for (int u = 2; u < 6; ++u){ w = cmul(w,w1); b0[u]=cmul(b0[u],w); b1[u]=cmul(b1[u],w); }
        ob = (tid - p*SC) + SC*6*p;
    }
    __syncthreads();
    if (act) {
        #pragma unroll
        for (int u = 0; u < 6; ++u) stp(buf, ob + SC*u, b0[u], b1[u]);
    }
    __syncthreads();
}

__device__ __forceinline__ void fused5K5_ip(float2* __restrict__ buf,
                                            const float4* __restrict__ KI,
                                            int cpair, int tid)
{
    constexpr float STEP = PI2 / 1080.0f;
    const float4* Kc = KI + cpair*1080;
    const bool act = tid < 216;
    float2 d0[5], d1[5];
    if (act) {
        float2 a0[5],a1[5],s0[5],s1[5];
        #pragma unroll
        for (int u = 0; u < 5; ++u) ldp(buf, tid + 216*u, a0[u], a1[u]);
        dft5<-1>(a0,s0); dft5<-1>(a1,s1);
        #pragma unroll
        for (int u = 0; u < 5; ++u) {
            float4 kk = Kc[tid + 216*u];
            s0[u] = cmul(s0[u], make_float2(kk.x,kk.y));
            s1[u] = cmul(s1[u], make_float2(kk.z,kk.w));
        }
        dft5<1>(s0,d0); dft5<1>(s1,d1);
        float sv, cv; __sincosf(STEP*(float)tid, &sv, &cv);
        float2 w1 = make_float2(cv,sv), w = w1;
        d0[1]=cmul(d0[1],w); d1[1]=cmul(d1[1],w);
        #pragma unroll
        for (int u = 2; u < 5; ++u){ w = cmul(w,w1); d0[u]=cmul(d0[u],w); d1[u]=cmul(d1[u],w); }
    }
    __syncthreads();
    if (act) {
        #pragma unroll
        for (int u = 0; u < 5; ++u) stp(buf, 5*tid + u, d0[u], d1[u]);
    }
    __syncthreads();
}

__device__ __forceinline__ void fin6_crop_pair(const float2* __restrict__ src,
                                               float2* __restrict__ Zp,
                                               int c0, int tid)
{
    float4* gc = (float4*)(Zp + c0);
    for (int m = tid; m < 180; m += 256) {
        float2 a0[6],a1[6],b0[6],b1[6];
        #pragma unroll
        for (int t = 0; t < 6; ++t) ldp(src, m + 180*t, a0[t], a1[t]);
        dft6<1>(a0,b0); dft6<1>(a1,b1);
        gc[(m+270)*960] = pk(b0[0], b1[0]);
        if (m < 90)  gc[(m+450)*960] = pk(b0[1], b1[1]);
        if (m >= 90) gc[(m-90)*960]  = pk(b0[4], b1[4]);
        gc[(m+90)*960]  = pk(b0[5], b1[5]);
    }
}

// ============ kernels ============

// K13: row forward FFTs. Blocks [0,1080): x pairs (plane pp, rows 2r,2r+1,
// z = img_a + i*img_b). Blocks [1080,1620): h single rows (old b64 path).
__global__ __launch_bounds__(256,5) void k_row_fwd(const float* __restrict__ x,
                                                   const float* __restrict__ h,
                                                   float2* __restrict__ Z,
                                                   float2* __restrict__ Hrow)
{
    __shared__ float4 sb[IDX4SZ(1920)];
    const int tid = threadIdx.x;
    if (blockIdx.x < 1080) {
        const int pp = blockIdx.x / 270;
        const int r0 = (blockIdx.x % 270) * 2;
        const float* xa = x + ((2*pp  )*540 + r0)*960;
        const float* xb = x + ((2*pp+1)*540 + r0)*960;
        rp_s1_fwd(xa, xb, sb, tid); __syncthreads();
        rp_mid8_ip<-1>(sb, tid);
        rp_mid6_ip<-1>(sb, tid);
        float2* Zr0 = Z + (pp*540 + r0)*1920;
        rp_fin5_storeZ(sb, Zr0, Zr0 + 1920, tid);
    } else {
        float2* bA = (float2*)sb;
        float2* bB = bA + IDXSZ(1920);
        const int r = blockIdx.x - 1080;
        row_s1_fwd_h(h + r*960, bA, tid); __syncthreads();
        mid_stage<-1,8,240, 8>(bA, bB, tid); __syncthreads();
        mid_stage<-1,6, 30,64>(bB, bA, tid); __syncthreads();
        row_fin5_store_h(bA, Hrow + r*1920, tid);
    }
}

// K2: column FFTs of Hrow (pair/thread, dbuf) + build pair-interleaved KI.
__global__ __launch_bounds__(256,4) void k_col_fft_h_buildK(const float2* __restrict__ Hrow,
                                                            const float* __restrict__ mu1,
                                                            float4* __restrict__ KI)
{
    __shared__ float2 bA[IDXPSZ(2160)], bB[IDXPSZ(2160)];
    const int tid = threadIdx.x;
    const int xcd = blockIdx.x & 7, idx = blockIdx.x >> 3;
    const int cpair = xcd*120 + idx, c0 = cpair*2;
    col_s1_fwd_pair(Hrow, c0, bA, tid);  __syncthreads();
    mid_pair<-1,180, 6>(bA, bB, tid);    __syncthreads();
    mid_pair<-1, 30,36>(bB, bA, tid);    __syncthreads();
    const float sc = mu1[4] / ((1.0f + 1e-6f) * 2073600.0f);
    const float cos0 = __cosf(PI2 * (float)(c0  ) * (1.0f/1920.0f));
    const float cos1 = __cosf(PI2 * (float)(c0+1) * (1.0f/1920.0f));
    float4* Kc = KI + cpair*1080;
    for (int p = tid; p < 216; p += 256) {
        float2 a0[5],a1[5],b0[5],b1[5];
        #pragma unroll
        for (int u = 0; u < 5; ++u) ldp(bA, p + 216*u, a0[u], a1[u]);
        dft5<-1>(a0,b0); dft5<-1>(a1,b1);
        #pragma unroll
        for (int u = 0; u < 5; ++u) {
            const int k = p + 216*u;
            const float cosk = __cosf(PI2 * (float)k * (1.0f/1080.0f));
            float m0 = b0[u].x*b0[u].x + b0[u].y*b0[u].y;
            float m1 = b1[u].x*b1[u].x + b1[u].y*b1[u].y;
            float f0 = sc / (1e-6f*m0 + 1e-5f*(4.0f - 2.0f*cosk - 2.0f*cos0) + 4e-5f);
            float f1 = sc / (1e-6f*m1 + 1e-5f*(4.0f - 2.0f*cosk - 2.0f*cos1) + 4e-5f);
            Kc[k] = make_float4(f0*b0[u].x, -f0*b0[u].y, f1*b1[u].x, -f1*b1[u].y);
        }
    }
}

// K4: fused column pass, IN-PLACE single LDS buffer (18.4KB, 8 blocks/CU).
// s1(6,global) -> mid6 -> mid6 -> fused5K5 -> mid6 -> mid6 -> fin6+crop.
// XCD-chunked swizzle: xcd = bid&7, idx = bid>>3 in [0,480).
__global__ __launch_bounds__(256,8) void k_col_fused(float2* __restrict__ Z,
                                                     const float4* __restrict__ KI)
{
    __shared__ float2 buf[IDXPSZ(2160)];
    const int tid = threadIdx.x;
    const int xcd = blockIdx.x & 7, idx = blockIdx.x >> 3;
    const int pp  = idx / 120;
    const int cpair = xcd*120 + (idx - pp*120), c0 = cpair*2;
    float2* Zp = Z + pp*540*1920;
    col_s1_fwd_pair(Zp, c0, buf, tid);  __syncthreads();
    mid_pair_ip<-1,180, 6>(buf, tid);
    mid_pair_ip<-1, 30,36>(buf, tid);
    fused5K5_ip(buf, KI, cpair, tid);
    mid_pair_ip< 1,216, 5>(buf, tid);
    mid_pair_ip< 1, 36,30>(buf, tid);
    fin6_crop_pair(buf, Zp, c0, tid);
}

// K5: row inverse FFTs, paired rows + crop + split into real outputs.
__global__ __launch_bounds__(256,5) void k_row_inv_out(const float2* __restrict__ Z,
                                                       float* __restrict__ out)
{
    __shared__ float4 sb[IDX4SZ(1920)];
    const int tid = threadIdx.x;
    const int pp = blockIdx.x / 270;
    const int r0 = (blockIdx.x % 270) * 2;
    const float2* Zr0 = Z + (pp*540 + r0)*1920;
    rp_s1_inv(Zr0, Zr0 + 1920, sb, tid); __syncthreads();
    rp_mid8_ip<1>(sb, tid);
    rp_mid6_ip<1>(sb, tid);
    float* oa0 = out + ((2*pp  )*540 + r0)*960;
    float* ob0 = out + ((2*pp+1)*540 + r0)*960;
    rp_fin5_crop(sb, oa0, ob0, oa0 + 960, ob0 + 960, tid);
}

extern "C" void kernel_launch(void* const* d_in, const int* in_sizes, int n_in,
                              void* d_out, int out_size, void* d_ws, size_t ws_size,
                              hipStream_t stream)
{
    (void)in_sizes; (void)n_in; (void)out_size; (void)ws_size;
    const float* x   = (const float*)d_in[0];
    const float* h   = (const float*)d_in[1];
    const float* mu1 = (const float*)d_in[2];
    float*       out = (float*)d_out;

    // ws layout: KI (960*1080 f4 = 16.6MB) | Z (4*540*1920 f2 = 33.2MB) |
    // Hrow (540*1920 f2 = 8.3MB) -- no aliasing (K13 writes Z and Hrow).
    float4* KI   = (float4*)d_ws;
    float2* Z    = (float2*)(KI + 960*1080);
    float2* Hrow = Z + 4*540*1920;

    k_row_fwd         <<<1620,   256, 0, stream>>>(x, h, Z, Hrow);
    k_col_fft_h_buildK<<<960,    256, 0, stream>>>(Hrow, mu1, KI);
    k_col_fused       <<<3840,   256, 0, stream>>>(Z, KI);
    k_row_inv_out     <<<1080,   256, 0, stream>>>(Z, out);
}

// Round 11
// 83.409 us; speedup vs baseline: 1.2005x; 1.0115x over previous
//
#include <hip/hip_runtime.h>

// Le-ADMM reduction: state resets each iteration => output is one linear
// circular filter: out = crop_shift( IFFT2( K . FFT2(pad(x)) ) ),
// K = mu1[4]/((1+1e-6)*FH*FW) * conj(Hp) / (1e-6|Hp|^2 + 1e-5*PsiTPsi + 4e-5).
// Pairs packed z = x_a + i*x_b (K Hermitian => both results real).
//
// R10: K4 = B=4 columns/block + radix-{10,12,9} high-radix IN-PLACE.
// R6's high-radix failed because items/pass fell to 90-120 (<180 starves
// 256 threads); B=4 doubles items -> 216/180/240/180/216, all >=180.
// 5 passes / 7 barriers (was 7/11), LDS traffic -33%, sincos layers 7->5.
// K4 counters (R9) showed LDS-issue + VALU-issue summing to ~100% ->
// instruction removal is the only lever. Keeps: R9 paired row kernels,
// R7 in-place columns concept, R5 float4 pair LDS, R3 XCD swizzle.

#define PI2 6.2831853071795864f

__device__ __forceinline__ float2 cadd(float2 a, float2 b){ return make_float2(a.x+b.x, a.y+b.y); }
__device__ __forceinline__ float2 csub(float2 a, float2 b){ return make_float2(a.x-b.x, a.y-b.y); }
__device__ __forceinline__ float2 cmul(float2 a, float2 b){ return make_float2(a.x*b.x - a.y*b.y, a.x*b.y + a.y*b.x); }
__device__ __forceinline__ float4 pk(float2 a, float2 b){ return make_float4(a.x,a.y,b.x,b.y); }

// b64 pad (h single-row path): +1 f2 per 16.
__device__ __forceinline__ int IDX(int a){ return a + (a >> 4); }
#define IDXSZ(n) ((n) + ((n) >> 4))
// Column K2 f2 pad: +2 per 32 (float4-aligned).
__device__ __forceinline__ int IDXP(int a){ return a + ((a >> 5) << 1); }
#define IDXPSZ(n) ((n) + (((n) >> 5) << 1) + 4)
// float4-slot pad: +1 slot per 16.
__device__ __forceinline__ int IDX4(int a){ return a + (a >> 4); }
#define IDX4SZ(n) ((n) + ((n) >> 4) + 2)

// K2 pair LDS (f2 buffer, float4 access).
__device__ __forceinline__ void ldp(const float2* __restrict__ b, int pos,
                                    float2& v0, float2& v1){
    const float4 t = *(const float4*)&b[IDXP(2*pos)];
    v0 = make_float2(t.x,t.y); v1 = make_float2(t.z,t.w);
}
__device__ __forceinline__ void stp(float2* __restrict__ b, int pos,
                                    float2 v0, float2 v1){
    *(float4*)&b[IDXP(2*pos)] = pk(v0, v1);
}
// Row-pair LDS (float4 buffer).
__device__ __forceinline__ void ld4(const float4* __restrict__ b, int pos,
                                    float2& v0, float2& v1){
    const float4 t = b[IDX4(pos)];
    v0 = make_float2(t.x,t.y); v1 = make_float2(t.z,t.w);
}
__device__ __forceinline__ void st4(float4* __restrict__ b, int pos,
                                    float2 v0, float2 v1){
    b[IDX4(pos)] = pk(v0, v1);
}
// K4 B=4 LDS: slot = 2*pos + g (g = pair group 0/1).
__device__ __forceinline__ void ld4g(const float4* __restrict__ b, int pos, int g,
                                     float2& v0, float2& v1){
    const float4 t = b[IDX4(2*pos+g)];
    v0 = make_float2(t.x,t.y); v1 = make_float2(t.z,t.w);
}
__device__ __forceinline__ void st4g(float4* __restrict__ b, int pos, int g,
                                     float2 v0, float2 v1){
    b[IDX4(2*pos+g)] = pk(v0, v1);
}

template<int DIR>
__device__ __forceinline__ void dft3(float2 x0, float2 x1, float2 x2,
                                     float2& y0, float2& y1, float2& y2)
{
    constexpr float s3 = (float)DIR * 0.8660254037844386f;
    float2 t = cadd(x1, x2), u = csub(x1, x2);
    float2 m = make_float2(x0.x - 0.5f*t.x, x0.y - 0.5f*t.y);
    float2 iu = make_float2(-s3*u.y, s3*u.x);
    y0 = cadd(x0, t); y1 = cadd(m, iu); y2 = csub(m, iu);
}

template<int DIR>
__device__ __forceinline__ void dft4(float2 a0, float2 a1, float2 a2, float2 a3,
                                     float2& b0, float2& b1, float2& b2, float2& b3)
{
    float2 t0 = cadd(a0,a2), t1 = csub(a0,a2), t2 = cadd(a1,a3), t3 = csub(a1,a3);
    float2 j3 = make_float2(-(float)DIR*t3.y, (float)DIR*t3.x);
    b0 = cadd(t0,t2); b2 = csub(t0,t2); b1 = cadd(t1,j3); b3 = csub(t1,j3);
}

template<int DIR>
__device__ __forceinline__ void dft6(const float2 a[6], float2 b[6])
{
    float2 e0,e1,e2,o0,o1,o2;
    dft3<DIR>(a[0],a[2],a[4], e0,e1,e2);
    dft3<DIR>(a[1],a[3],a[5], o0,o1,o2);
    constexpr float s3 = (float)DIR * 0.8660254037844386f;
    float2 w1 = make_float2( 0.5f, s3);
    float2 w2 = make_float2(-0.5f, s3);
    float2 t1 = cmul(w1,o1), t2 = cmul(w2,o2);
    b[0]=cadd(e0,o0); b[3]=csub(e0,o0);
    b[1]=cadd(e1,t1); b[4]=csub(e1,t1);
    b[2]=cadd(e2,t2); b[5]=csub(e2,t2);
}

template<int DIR>
__device__ __forceinline__ void dft8(const float2 a[8], float2 b[8])
{
    float2 e0,e1,e2,e3,o0,o1,o2,o3;
    dft4<DIR>(a[0],a[2],a[4],a[6], e0,e1,e2,e3);
    dft4<DIR>(a[1],a[3],a[5],a[7], o0,o1,o2,o3);
    constexpr float c = 0.70710678118654752f;
    float2 w1 = make_float2( c, (float)DIR*c);
    float2 w3 = make_float2(-c, (float)DIR*c);
    float2 t1 = cmul(w1,o1);
    float2 t2 = make_float2(-(float)DIR*o2.y, (float)DIR*o2.x);
    float2 t3 = cmul(w3,o3);
    b[0]=cadd(e0,o0); b[4]=csub(e0,o0);
    b[1]=cadd(e1,t1); b[5]=csub(e1,t1);
    b[2]=cadd(e2,t2); b[6]=csub(e2,t2);
    b[3]=cadd(e3,t3); b[7]=csub(e3,t3);
}

template<int DIR>
__device__ __forceinline__ void dft5(const float2 a[5], float2 b[5])
{
    constexpr float C1 = 0.30901699437494742f, S1c = 0.9510565162951535f;
    constexpr float C2 = -0.8090169943749475f, S2c = 0.5877852522924731f;
    float2 t1 = cadd(a[1],a[4]), t2 = cadd(a[2],a[3]), d1 = csub(a[1],a[4]), d2 = csub(a[2],a[3]);
    float2 m1 = make_float2(a[0].x + C1*t1.x + C2*t2.x, a[0].y + C1*t1.y + C2*t2.y);
    float2 m2 = make_float2(a[0].x + C2*t1.x + C1*t2.x, a[0].y + C2*t1.y + C1*t2.y);
    float2 e1 = make_float2(S1c*d1.x + S2c*d2.x, S1c*d1.y + S2c*d2.y);
    float2 e2 = make_float2(S2c*d1.x - S1c*d2.x, S2c*d1.y - S1c*d2.y);
    float2 ie1 = make_float2(-(float)DIR*e1.y, (float)DIR*e1.x);
    float2 ie2 = make_float2(-(float)DIR*e2.y, (float)DIR*e2.x);
    b[0] = make_float2(a[0].x + t1.x + t2.x, a[0].y + t1.y + t2.y);
    b[1] = cadd(m1, ie1); b[4] = csub(m1, ie1);
    b[2] = cadd(m2, ie2); b[3] = csub(m2, ie2);
}

// dft9 / dft10 / dft12 (verified in R6 -- lifted verbatim).
template<int DIR>
__device__ __forceinline__ void dft9(const float2 a[9], float2 b[9])
{
    float2 C0[3], C1[3], C2[3];
    dft3<DIR>(a[0],a[3],a[6], C0[0],C0[1],C0[2]);
    dft3<DIR>(a[1],a[4],a[7], C1[0],C1[1],C1[2]);
    dft3<DIR>(a[2],a[5],a[8], C2[0],C2[1],C2[2]);
    const float2 w91 = make_float2(0.7660444431189780f, (float)DIR*0.6427876096865393f);
    const float2 w92 = make_float2(0.1736481776669304f, (float)DIR*0.9848077530122081f);
    const float2 w94 = make_float2(-0.9396926207859084f, (float)DIR*0.3420201433256687f);
    C1[1]=cmul(C1[1],w91); C1[2]=cmul(C1[2],w92);
    C2[1]=cmul(C2[1],w92); C2[2]=cmul(C2[2],w94);
    dft3<DIR>(C0[0],C1[0],C2[0], b[0],b[3],b[6]);
    dft3<DIR>(C0[1],C1[1],C2[1], b[1],b[4],b[7]);
    dft3<DIR>(C0[2],C1[2],C2[2], b[2],b[5],b[8]);
}

template<int DIR>
__device__ __forceinline__ void dft10(const float2 a[10], float2 b[10])
{
    float2 ae[5] = {a[0],a[2],a[4],a[6],a[8]};
    float2 ao[5] = {a[1],a[3],a[5],a[7],a[9]};
    float2 E[5], O[5];
    dft5<DIR>(ae, E); dft5<DIR>(ao, O);
    const float2 w1 = make_float2( 0.8090169943749475f, (float)DIR*0.5877852522924731f);
    const float2 w2 = make_float2( 0.3090169943749474f, (float)DIR*0.9510565162951535f);
    const float2 w3 = make_float2(-0.3090169943749474f, (float)DIR*0.9510565162951535f);
    const float2 w4 = make_float2(-0.8090169943749475f, (float)DIR*0.5877852522924731f);
    float2 t1 = cmul(O[1],w1), t2 = cmul(O[2],w2), t3 = cmul(O[3],w3), t4 = cmul(O[4],w4);
    b[0]=cadd(E[0],O[0]); b[5]=csub(E[0],O[0]);
    b[1]=cadd(E[1],t1);   b[6]=csub(E[1],t1);
    b[2]=cadd(E[2],t2);   b[7]=csub(E[2],t2);
    b[3]=cadd(E[3],t3);   b[8]=csub(E[3],t3);
    b[4]=cadd(E[4],t4);   b[9]=csub(E[4],t4);
}

template<int DIR>
__device__ __forceinline__ void dft12(const float2 a[12], float2 b[12])
{
    float2 C0[4], C1[4], C2[4];
    dft4<DIR>(a[0],a[3],a[6],a[9],  C0[0],C0[1],C0[2],C0[3]);
    dft4<DIR>(a[1],a[4],a[7],a[10], C1[0],C1[1],C1[2],C1[3]);
    dft4<DIR>(a[2],a[5],a[8],a[11], C2[0],C2[1],C2[2],C2[3]);
    const float2 w121 = make_float2(0.8660254037844386f, (float)DIR*0.5f);
    const float2 w122 = make_float2(0.5f, (float)DIR*0.8660254037844386f);
    const float2 w124 = make_float2(-0.5f, (float)DIR*0.8660254037844386f);
    C1[1]=cmul(C1[1],w121); C1[2]=cmul(C1[2],w122);
    C1[3]=make_float2(-(float)DIR*C1[3].y, (float)DIR*C1[3].x);
    C2[1]=cmul(C2[1],w122); C2[2]=cmul(C2[2],w124);
    C2[3]=make_float2(-C2[3].x, -C2[3].y);
    dft3<DIR>(C0[0],C1[0],C2[0], b[0],b[4],b[8]);
    dft3<DIR>(C0[1],C1[1],C2[1], b[1],b[5],b[9]);
    dft3<DIR>(C0[2],C1[2],C2[2], b[2],b[6],b[10]);
    dft3<DIR>(C0[3],C1[3],C2[3], b[3],b[7],b[11]);
}

// ============ h single-row path (b64, dbuf) ============

__device__ __forceinline__ void row_s1_fwd_h(const float* __restrict__ xa,
                                             float2* __restrict__ bA, int tid)
{
    constexpr float STEP = -PI2 / 1920.0f;
    const float2 z = make_float2(0.f,0.f);
    for (int p = tid; p < 240; p += 256) {
        float2 a[8], b[8];
        a[0]=z; a[1]=z; a[6]=z; a[7]=z;
        a[2] = make_float2(xa[p],     0.f);
        a[3] = make_float2(xa[p+240], 0.f);
        a[4] = make_float2(xa[p+480], 0.f);
        a[5] = make_float2(xa[p+720], 0.f);
        dft8<-1>(a,b);
        float sv, cv; __sincosf(STEP * (float)p, &sv, &cv);
        float2 w1 = make_float2(cv, sv), w = w1;
        b[1] = cmul(b[1], w);
        #pragma unroll
        for (int u = 2; u < 8; ++u) { w = cmul(w, w1); b[u] = cmul(b[u], w); }
        #pragma unroll
        for (int u = 0; u < 8; ++u) bA[IDX(8*p + u)] = b[u];
    }
}

template<int DIR, int R, int NCUR, int S>
__device__ __forceinline__ void mid_stage(const float2* __restrict__ src,
                                          float2* __restrict__ dst, int tid)
{
    constexpr int M  = NCUR / R;
    constexpr int NB = M * S;
    constexpr float STEP = (float)DIR * PI2 / (float)NCUR;
    for (int i = tid; i < NB; i += 256) {
        const int p = i / S;
        float2 a[R], b[R];
        #pragma unroll
        for (int t = 0; t < R; ++t) a[t] = src[IDX(i + S*M*t)];
        if constexpr (R == 6) dft6<DIR>(a,b); else dft8<DIR>(a,b);
        float sv, cv; __sincosf(STEP * (float)p, &sv, &cv);
        float2 w1 = make_float2(cv, sv), w = w1;
        b[1] = cmul(b[1], w);
        #pragma unroll
        for (int u = 2; u < R; ++u) { w = cmul(w, w1); b[u] = cmul(b[u], w); }
        const int ob = (i - p*S) + S*(R*p);
        #pragma unroll
        for (int u = 0; u < R; ++u) dst[IDX(ob + S*u)] = b[u];
    }
}

__device__ __forceinline__ void row_fin5_store_h(const float2* __restrict__ src,
                                                 float2* __restrict__ gdst, int tid)
{
    for (int q = tid; q < 384; q += 256) {
        float2 a[5], b[5];
        #pragma unroll
        for (int u = 0; u < 5; ++u) a[u] = src[IDX(q + 384*u)];
        dft5<-1>(a,b);
        #pragma unroll
        for (int u = 0; u < 5; ++u) gdst[q + 384*u] = b[u];
    }
}

// ============ row-pair path (float4, in-place) ============

__device__ __forceinline__ void rp_s1_fwd(const float* __restrict__ xa,
                                          const float* __restrict__ xb,
                                          float4* __restrict__ sb, int tid)
{
    constexpr float STEP = -PI2 / 1920.0f;
    const float2 z = make_float2(0.f,0.f);
    for (int p = tid; p < 240; p += 256) {
        float2 a0[8], a1[8], b0[8], b1[8];
        a0[0]=a0[1]=a0[6]=a0[7]=z; a1[0]=a1[1]=a1[6]=a1[7]=z;
        #pragma unroll
        for (int t = 0; t < 4; ++t) {
            a0[2+t] = make_float2(xa[p+240*t],     xb[p+240*t]);
            a1[2+t] = make_float2(xa[960+p+240*t], xb[960+p+240*t]);
        }
        dft8<-1>(a0,b0); dft8<-1>(a1,b1);
        float sv, cv; __sincosf(STEP*(float)p, &sv, &cv);
        float2 w1 = make_float2(cv,sv), w = w1;
        b0[1]=cmul(b0[1],w); b1[1]=cmul(b1[1],w);
        #pragma unroll
        for (int u = 2; u < 8; ++u){ w = cmul(w,w1); b0[u]=cmul(b0[u],w); b1[u]=cmul(b1[u],w); }
        #pragma unroll
        for (int u = 0; u < 8; ++u) st4(sb, 8*p+u, b0[u], b1[u]);
    }
}

__device__ __forceinline__ void rp_s1_inv(const float2* __restrict__ Zr0,
                                          const float2* __restrict__ Zr1,
                                          float4* __restrict__ sb, int tid)
{
    constexpr float STEP = PI2 / 1920.0f;
    for (int p = tid; p < 240; p += 256) {
        float2 a0[8], a1[8], b0[8], b1[8];
        #pragma unroll
        for (int t = 0; t < 8; ++t) { a0[t] = Zr0[p+240*t]; a1[t] = Zr1[p+240*t]; }
        dft8<1>(a0,b0); dft8<1>(a1,b1);
        float sv, cv; __sincosf(STEP*(float)p, &sv, &cv);
        float2 w1 = make_float2(cv,sv), w = w1;
        b0[1]=cmul(b0[1],w); b1[1]=cmul(b1[1],w);
        #pragma unroll
        for (int u = 2; u < 8; ++u){ w = cmul(w,w1); b0[u]=cmul(b0[u],w); b1[u]=cmul(b1[u],w); }
        #pragma unroll
        for (int u = 0; u < 8; ++u) st4(sb, 8*p+u, b0[u], b1[u]);
    }
}

template<int DIR>
__device__ __forceinline__ void rp_mid8_ip(float4* __restrict__ sb, int tid)
{
    constexpr float STEP = (float)DIR * PI2 / 240.0f;
    const bool act = tid < 240;
    float2 b0[8], b1[8]; int ob = 0;
    if (act) {
        const int p = tid >> 3;
        float2 a0[8], a1[8];
        #pragma unroll
        for (int t = 0; t < 8; ++t) ld4(sb, tid + 240*t, a0[t], a1[t]);
        dft8<DIR>(a0,b0); dft8<DIR>(a1,b1);
        float sv, cv; __sincosf(STEP*(float)p, &sv, &cv);
        float2 w1 = make_float2(cv,sv), w = w1;
        b0[1]=cmul(b0[1],w); b1[1]=cmul(b1[1],w);
        #pragma unroll
        for (int u = 2; u < 8; ++u){ w = cmul(w,w1); b0[u]=cmul(b0[u],w); b1[u]=cmul(b1[u],w); }
        ob = (tid - 8*p) + 64*p;
    }
    __syncthreads();
    if (act) {
        #pragma unroll
        for (int u = 0; u < 8; ++u) st4(sb, ob + 8*u, b0[u], b1[u]);
    }
    __syncthreads();
}

template<int DIR>
__device__ __forceinline__ void rp_mid6_ip(float4* __restrict__ sb, int tid)
{
    constexpr float STEP = (float)DIR * PI2 / 30.0f;
    float2 c0[6], c1[6], d0[6], d1[6]; int ob0, ob1 = 0;
    {
        const int i = tid, p = i >> 6;
        float2 a0[6], a1[6];
        #pragma unroll
        for (int t = 0; t < 6; ++t) ld4(sb, i + 320*t, a0[t], a1[t]);
        dft6<DIR>(a0,c0); dft6<DIR>(a1,c1);
        float sv, cv; __sincosf(STEP*(float)p, &sv, &cv);
        float2 w1 = make_float2(cv,sv), w = w1;
        c0[1]=cmul(c0[1],w); c1[1]=cmul(c1[1],w);
        #pragma unroll
        for (int u = 2; u < 6; ++u){ w = cmul(w,w1); c0[u]=cmul(c0[u],w); c1[u]=cmul(c1[u],w); }
        ob0 = (i - 64*p) + 384*p;
    }
    const bool act2 = tid < 64;
    if (act2) {
        const int i = 256 + tid;                 // p = 4
        float2 a0[6], a1[6];
        #pragma unroll
        for (int t = 0; t < 6; ++t) ld4(sb, i + 320*t, a0[t], a1[t]);
        dft6<DIR>(a0,d0); dft6<DIR>(a1,d1);
        float sv, cv; __sincosf(STEP*4.0f, &sv, &cv);
        float2 w1 = make_float2(cv,sv), w = w1;
        d0[1]=cmul(d0[1],w); d1[1]=cmul(d1[1],w);
        #pragma unroll
        for (int u = 2; u < 6; ++u){ w = cmul(w,w1); d0[u]=cmul(d0[u],w); d1[u]=cmul(d1[u],w); }
        ob1 = tid + 1536;
    }
    __syncthreads();
    {
        #pragma unroll
        for (int u = 0; u < 6; ++u) st4(sb, ob0 + 64*u, c0[u], c1[u]);
    }
    if (act2) {
        #pragma unroll
        for (int u = 0; u < 6; ++u) st4(sb, ob1 + 64*u, d0[u], d1[u]);
    }
    __syncthreads();
}

__device__ __forceinline__ void rp_fin5_storeZ(const float4* __restrict__ sb,
                                               float2* __restrict__ Zr0,
                                               float2* __restrict__ Zr1, int tid)
{
    for (int q = tid; q < 384; q += 256) {
        float2 a0[5],a1[5],b0[5],b1[5];
        #pragma unroll
        for (int u = 0; u < 5; ++u) ld4(sb, q + 384*u, a0[u], a1[u]);
        dft5<-1>(a0,b0); dft5<-1>(a1,b1);
        #pragma unroll
        for (int u = 0; u < 5; ++u) { Zr0[q+384*u] = b0[u]; Zr1[q+384*u] = b1[u]; }
    }
}

__device__ __forceinline__ void rp_fin5_crop(const float4* __restrict__ sb,
                                             float* __restrict__ oa0, float* __restrict__ ob0,
                                             float* __restrict__ oa1, float* __restrict__ ob1,
                                             int tid)
{
    for (int q = tid; q < 384; q += 256) {
        float2 a0[5],a1[5],b0[5],b1[5];
        #pragma unroll
        for (int u = 0; u < 5; ++u) ld4(sb, q + 384*u, a0[u], a1[u]);
        dft5<1>(a0,b0); dft5<1>(a1,b1);
        oa0[q+480] = b0[0].x; ob0[q+480] = b0[0].y;
        oa1[q+480] = b1[0].x; ob1[q+480] = b1[0].y;
        if (q < 96)   { oa0[q+864] = b0[1].x; ob0[q+864] = b0[1].y;
                        oa1[q+864] = b1[1].x; ob1[q+864] = b1[1].y; }
        if (q >= 288) { oa0[q-288] = b0[3].x; ob0[q-288] = b0[3].y;
                        oa1[q-288] = b1[3].x; ob1[q-288] = b1[3].y; }
        oa0[q+96]  = b0[4].x; ob0[q+96]  = b0[4].y;
        oa1[q+96]  = b1[4].x; ob1[q+96]  = b1[4].y;
    }
}

// ============ K2 column path (R7: sincos, pair-per-thread, dbuf) ============

__device__ __forceinline__ void col_s1_fwd_pair(const float2* __restrict__ g, int c0,
                                                float2* __restrict__ bA, int tid)
{
    constexpr float STEP = -PI2 / 1080.0f;
    const float2 z = make_float2(0.f,0.f);
    const float4* gc = (const float4*)(g + c0);
    for (int p = tid; p < 180; p += 256) {
        float2 a0[6], a1[6], b0[6], b1[6];
        a0[0]=a0[5]=a1[0]=a1[5]=z;
        if (p >= 90) { float4 t = gc[(p-90)*960]; a0[1]=make_float2(t.x,t.y); a1[1]=make_float2(t.z,t.w); }
        else         { a0[1]=a1[1]=z; }
        { float4 t = gc[(p+90)*960];  a0[2]=make_float2(t.x,t.y); a1[2]=make_float2(t.z,t.w); }
        { float4 t = gc[(p+270)*960]; a0[3]=make_float2(t.x,t.y); a1[3]=make_float2(t.z,t.w); }
        if (p < 90)  { float4 t = gc[(p+450)*960]; a0[4]=make_float2(t.x,t.y); a1[4]=make_float2(t.z,t.w); }
        else         { a0[4]=a1[4]=z; }
        dft6<-1>(a0,b0); dft6<-1>(a1,b1);
        float sv, cv; __sincosf(STEP*(float)p, &sv, &cv);
        float2 w1 = make_float2(cv,sv), w = w1;
        b0[1]=cmul(b0[1],w); b1[1]=cmul(b1[1],w);
        #pragma unroll
        for (int u = 2; u < 6; ++u){ w = cmul(w,w1); b0[u]=cmul(b0[u],w); b1[u]=cmul(b1[u],w); }
        #pragma unroll
        for (int u = 0; u < 6; ++u) stp(bA, 6*p + u, b0[u], b1[u]);
    }
}

template<int DIR, int NCUR, int SC>
__device__ __forceinline__ void mid_pair(const float2* __restrict__ src,
                                         float2* __restrict__ dst, int tid)
{
    constexpr int NB = 180;
    constexpr float STEP = (float)DIR * PI2 / (float)NCUR;
    for (int ic = tid; ic < NB; ic += 256) {
        const int p = ic / SC;
        float2 a0[6], a1[6], b0[6], b1[6];
        #pragma unroll
        for (int t = 0; t < 6; ++t) ldp(src, ic + NB*t, a0[t], a1[t]);
        dft6<DIR>(a0,b0); dft6<DIR>(a1,b1);
        float sv, cv; __sincosf(STEP*(float)p, &sv, &cv);
        float2 w1 = make_float2(cv,sv), w = w1;
        b0[1]=cmul(b0[1],w); b1[1]=cmul(b1[1],w);
        #pragma unroll
        for (int u = 2; u < 6; ++u){ w = cmul(w,w1); b0[u]=cmul(b0[u],w); b1[u]=cmul(b1[u],w); }
        const int ob = (ic - p*SC) + SC*6*p;
        #pragma unroll
        for (int u = 0; u < 6; ++u) stp(dst, ob + SC*u, b0[u], b1[u]);
    }
}

// ============ K4 B=4 high-radix in-place pieces ============

// s1 radix-10 from global (zero-pad: a[3..6] always, a[2] if p>=54,
// a[7] if p<54; global row = n-270). Writes only; barrier at end.
__device__ __forceinline__ void c4_s1_fwd10(const float2* __restrict__ Zp, int c0,
                                            float4* __restrict__ sb, int tid)
{
    constexpr float STEP = -PI2 / 1080.0f;
    const float2 z = make_float2(0.f,0.f);
    const float4* gc = (const float4*)(Zp + c0);
    const bool act = tid < 216;
    if (act) {
        const int g = tid & 1, p = tid >> 1;
        float2 a0[10], a1[10], b0[10], b1[10];
        a0[0]=a0[1]=a0[8]=a0[9]=z; a1[0]=a1[1]=a1[8]=a1[9]=z;
        if (p >= 54) { float4 t = gc[(p-54)*960+g]; a0[2]=make_float2(t.x,t.y); a1[2]=make_float2(t.z,t.w); }
        else         { a0[2]=a1[2]=z; }
        { float4 t = gc[(p+54)*960+g];  a0[3]=make_float2(t.x,t.y); a1[3]=make_float2(t.z,t.w); }
        { float4 t = gc[(p+162)*960+g]; a0[4]=make_float2(t.x,t.y); a1[4]=make_float2(t.z,t.w); }
        { float4 t = gc[(p+270)*960+g]; a0[5]=make_float2(t.x,t.y); a1[5]=make_float2(t.z,t.w); }
        { float4 t = gc[(p+378)*960+g]; a0[6]=make_float2(t.x,t.y); a1[6]=make_float2(t.z,t.w); }
        if (p < 54)  { float4 t = gc[(p+486)*960+g]; a0[7]=make_float2(t.x,t.y); a1[7]=make_float2(t.z,t.w); }
        else         { a0[7]=a1[7]=z; }
        dft10<-1>(a0,b0); dft10<-1>(a1,b1);
        float sv, cv; __sincosf(STEP*(float)p, &sv, &cv);
        float2 w1 = make_float2(cv,sv), w = w1;
        b0[1]=cmul(b0[1],w); b1[1]=cmul(b1[1],w);
        #pragma unroll
        for (int u = 2; u < 10; ++u){ w = cmul(w,w1); b0[u]=cmul(b0[u],w); b1[u]=cmul(b1[u],w); }
        #pragma unroll
        for (int u = 0; u < 10; ++u) st4g(sb, 10*p+u, g, b0[u], b1[u]);
    }
    __syncthreads();
}

// mid radix-12 in-place: NB = (NCUR/12)*SC = 90 per pair-group, 180 items.
template<int DIR, int NCUR, int SC>
__device__ __forceinline__ void c4_mid12_ip(float4* __restrict__ sb, int tid)
{
    constexpr int NB = (NCUR/12)*SC;   // 90
    constexpr float STEP = (float)DIR * PI2 / (float)NCUR;
    const bool act = tid < 2*NB;
    float2 b0[12], b1[12]; int ob = 0, g = 0;
    if (act) {
        g = tid & 1;
        const int ic = tid >> 1;
        const int p = ic / SC;
        float2 a0[12], a1[12];
        #pragma unroll
        for (int t = 0; t < 12; ++t) ld4g(sb, ic + NB*t, g, a0[t], a1[t]);
        dft12<DIR>(a0,b0); dft12<DIR>(a1,b1);
        float sv, cv; __sincosf(STEP*(float)p, &sv, &cv);
        float2 w1 = make_float2(cv,sv), w = w1;
        b0[1]=cmul(b0[1],w); b1[1]=cmul(b1[1],w);
        #pragma unroll
        for (int u = 2; u < 12; ++u){ w = cmul(w,w1); b0[u]=cmul(b0[u],w); b1[u]=cmul(b1[u],w); }
        ob = (ic - p*SC) + SC*12*p;
    }
    __syncthreads();
    if (act) {
        #pragma unroll
        for (int u = 0; u < 12; ++u) st4g(sb, ob + SC*u, g, b0[u], b1[u]);
    }
    __syncthreads();
}

// fused center: fwd-final radix-9 (twiddle-free; spectrum k = q+120u) ->
// *K -> inverse-first radix-9 (twiddle e^{+2pi i q u/1080}) -> scatter 9q+u.
__device__ __forceinline__ void c4_f9K9_ip(float4* __restrict__ sb,
                                           const float4* __restrict__ KI,
                                           int cg, int tid)
{
    constexpr float STEP = PI2 / 1080.0f;
    const bool act = tid < 240;
    float2 d0[9], d1[9]; int q = 0, g = 0;
    if (act) {
        g = tid & 1; q = tid >> 1;
        const float4* Kc = KI + (cg*2 + g)*1080;
        float2 a0[9], a1[9], s0[9], s1[9];
        #pragma unroll
        for (int u = 0; u < 9; ++u) ld4g(sb, q + 120*u, g, a0[u], a1[u]);
        dft9<-1>(a0,s0); dft9<-1>(a1,s1);
        #pragma unroll
        for (int u = 0; u < 9; ++u) {
            float4 kk = Kc[q + 120*u];
            s0[u] = cmul(s0[u], make_float2(kk.x,kk.y));
            s1[u] = cmul(s1[u], make_float2(kk.z,kk.w));
        }
        dft9<1>(s0,d0); dft9<1>(s1,d1);
        float sv, cv; __sincosf(STEP*(float)q, &sv, &cv);
        float2 w1 = make_float2(cv,sv), w = w1;
        d0[1]=cmul(d0[1],w); d1[1]=cmul(d1[1],w);
        #pragma unroll
        for (int u = 2; u < 9; ++u){ w = cmul(w,w1); d0[u]=cmul(d0[u],w); d1[u]=cmul(d1[u],w); }
    }
    __syncthreads();
    if (act) {
        #pragma unroll
        for (int u = 0; u < 9; ++u) st4g(sb, 9*q + u, g, d0[u], d1[u]);
    }
    __syncthreads();
}

// fin radix-10 (twiddle-free) + crop: n = q+108u; keep n<270 (ir=n+270):
// u=0,1, u=2 if q<54; n>=810 (ir=n-810): u=7 if q>=54, u=8,9.
__device__ __forceinline__ void c4_fin10_crop(const float4* __restrict__ sb,
                                              float2* __restrict__ Zp,
                                              int c0, int tid)
{
    const bool act = tid < 216;
    if (!act) return;
    const int g = tid & 1, q = tid >> 1;
    float4* gc = (float4*)(Zp + c0);
    float2 a0[10], a1[10], b0[10], b1[10];
    #pragma unroll
    for (int u = 0; u < 10; ++u) ld4g(sb, q + 108*u, g, a0[u], a1[u]);
    dft10<1>(a0,b0); dft10<1>(a1,b1);
    gc[(q+270)*960+g] = pk(b0[0], b1[0]);
    gc[(q+378)*960+g] = pk(b0[1], b1[1]);
    if (q < 54)  gc[(q+486)*960+g] = pk(b0[2], b1[2]);
    if (q >= 54) gc[(q-54)*960+g]  = pk(b0[7], b1[7]);
    gc[(q+54)*960+g]  = pk(b0[8], b1[8]);
    gc[(q+162)*960+g] = pk(b0[9], b1[9]);
}

// ============ kernels ============

// K13: row forward FFTs. Blocks [0,1080): x pairs; [1080,1620): h rows.
__global__ __launch_bounds__(256,5) void k_row_fwd(const float* __restrict__ x,
                                                   const float* __restrict__ h,
                                                   float2* __restrict__ Z,
                                                   float2* __restrict__ Hrow)
{
    __shared__ float4 sb[IDX4SZ(1920)];
    const int tid = threadIdx.x;
    if (blockIdx.x < 1080) {
        const int pp = blockIdx.x / 270;
        const int r0 = (blockIdx.x % 270) * 2;
        const float* xa = x + ((2*pp  )*540 + r0)*960;
        const float* xb = x + ((2*pp+1)*540 + r0)*960;
        rp_s1_fwd(xa, xb, sb, tid); __syncthreads();
        rp_mid8_ip<-1>(sb, tid);
        rp_mid6_ip<-1>(sb, tid);
        float2* Zr0 = Z + (pp*540 + r0)*1920;
        rp_fin5_storeZ(sb, Zr0, Zr0 + 1920, tid);
    } else {
        float2* bA = (float2*)sb;
        float2* bB = bA + IDXSZ(1920);
        const int r = blockIdx.x - 1080;
        row_s1_fwd_h(h + r*960, bA, tid); __syncthreads();
        mid_stage<-1,8,240, 8>(bA, bB, tid); __syncthreads();
        mid_stage<-1,6, 30,64>(bB, bA, tid); __syncthreads();
        row_fin5_store_h(bA, Hrow + r*1920, tid);
    }
}

// K2: column FFTs of Hrow (pair/thread, dbuf) + build pair-interleaved KI.
__global__ __launch_bounds__(256,4) void k_col_fft_h_buildK(const float2* __restrict__ Hrow,
                                                            const float* __restrict__ mu1,
                                                            float4* __restrict__ KI)
{
    __shared__ float2 bA[IDXPSZ(2160)], bB[IDXPSZ(2160)];
    const int tid = threadIdx.x;
    const int xcd = blockIdx.x & 7, idx = blockIdx.x >> 3;
    const int cpair = xcd*120 + idx, c0 = cpair*2;
    col_s1_fwd_pair(Hrow, c0, bA, tid);  __syncthreads();
    mid_pair<-1,180, 6>(bA, bB, tid);    __syncthreads();
    mid_pair<-1, 30,36>(bB, bA, tid);    __syncthreads();
    const float sc = mu1[4] / ((1.0f + 1e-6f) * 2073600.0f);
    const float cos0 = __cosf(PI2 * (float)(c0  ) * (1.0f/1920.0f));
    const float cos1 = __cosf(PI2 * (float)(c0+1) * (1.0f/1920.0f));
    float4* Kc = KI + cpair*1080;
    for (int p = tid; p < 216; p += 256) {
        float2 a0[5],a1[5],b0[5],b1[5];
        #pragma unroll
        for (int u = 0; u < 5; ++u) ldp(bA, p + 216*u, a0[u], a1[u]);
        dft5<-1>(a0,b0); dft5<-1>(a1,b1);
        #pragma unroll
        for (int u = 0; u < 5; ++u) {
            const int k = p + 216*u;
            const float cosk = __cosf(PI2 * (float)k * (1.0f/1080.0f));
            float m0 = b0[u].x*b0[u].x + b0[u].y*b0[u].y;
            float m1 = b1[u].x*b1[u].x + b1[u].y*b1[u].y;
            float f0 = sc / (1e-6f*m0 + 1e-5f*(4.0f - 2.0f*cosk - 2.0f*cos0) + 4e-5f);
            float f1 = sc / (1e-6f*m1 + 1e-5f*(4.0f - 2.0f*cosk - 2.0f*cos1) + 4e-5f);
            Kc[k] = make_float4(f0*b0[u].x, -f0*b0[u].y, f1*b1[u].x, -f1*b1[u].y);
        }
    }
}

// K4: B=4 columns/block, radix {10,12,[9 K 9],12,10}, IN-PLACE (36.7KB LDS,
// 4 blocks/CU). 5 passes / 7 barriers. Grid 1920; XCD swizzle: each XCD
// owns a 240-column slab for all 4 planes.
__global__ __launch_bounds__(256,4) void k_col_fused(float2* __restrict__ Z,
                                                     const float4* __restrict__ KI)
{
    __shared__ float4 sb[IDX4SZ(2160)];
    const int tid = threadIdx.x;
    const int xcd = blockIdx.x & 7, idx = blockIdx.x >> 3;   // idx in [0,240)
    const int pp  = idx / 60;
    const int cg  = xcd*60 + (idx - pp*60);                  // col-group [0,480)
    const int c0  = cg*4;
    float2* Zp = Z + pp*540*1920;
    c4_s1_fwd10(Zp, c0, sb, tid);
    c4_mid12_ip<-1,108,10>(sb, tid);
    c4_f9K9_ip(sb, KI, cg, tid);
    c4_mid12_ip< 1,120, 9>(sb, tid);
    c4_fin10_crop(sb, Zp, c0, tid);
}

// K5: row inverse FFTs, paired rows + crop + split into real outputs.
__global__ __launch_bounds__(256,5) void k_row_inv_out(const float2* __restrict__ Z,
                                                       float* __restrict__ out)
{
    __shared__ float4 sb[IDX4SZ(1920)];
    const int tid = threadIdx.x;
    const int pp = blockIdx.x / 270;
    const int r0 = (blockIdx.x % 270) * 2;
    const float2* Zr0 = Z + (pp*540 + r0)*1920;
    rp_s1_inv(Zr0, Zr0 + 1920, sb, tid); __syncthreads();
    rp_mid8_ip<1>(sb, tid);
    rp_mid6_ip<1>(sb, tid);
    float* oa0 = out + ((2*pp  )*540 + r0)*960;
    float* ob0 = out + ((2*pp+1)*540 + r0)*960;
    rp_fin5_crop(sb, oa0, ob0, oa0 + 960, ob0 + 960, tid);
}

extern "C" void kernel_launch(void* const* d_in, const int* in_sizes, int n_in,
                              void* d_out, int out_size, void* d_ws, size_t ws_size,
                              hipStream_t stream)
{
    (void)in_sizes; (void)n_in; (void)out_size; (void)ws_size;
    const float* x   = (const float*)d_in[0];
    const float* h   = (const float*)d_in[1];
    const float* mu1 = (const float*)d_in[2];
    float*       out = (float*)d_out;

    // ws layout: KI (960*1080 f4 = 16.6MB) | Z (4*540*1920 f2 = 33.2MB) |
    // Hrow (540*1920 f2 = 8.3MB).
    float4* KI   = (float4*)d_ws;
    float2* Z    = (float2*)(KI + 960*1080);
    float2* Hrow = Z + 4*540*1920;

    k_row_fwd         <<<1620,   256, 0, stream>>>(x, h, Z, Hrow);
    k_col_fft_h_buildK<<<960,    256, 0, stream>>>(Hrow, mu1, KI);
    k_col_fused       <<<1920,   256, 0, stream>>>(Z, KI);
    k_row_inv_out     <<<1080,   256, 0, stream>>>(Z, out);
}

// Round 12
// 73.546 us; speedup vs baseline: 1.3614x; 1.1341x over previous
//
#include <hip/hip_runtime.h>

// Le-ADMM reduction: state resets each iteration => output is one linear
// circular filter: out = crop_shift( IFFT2( K . FFT2(pad(x)) ) ),
// K = mu1[4]/((1+1e-6)*FH*FW) * conj(Hp) / (1e-6|Hp|^2 + 1e-5*PsiTPsi + 4e-5).
// Pairs packed z = x_a + i*x_b (K Hermitian => both results real).
//
// R11: PACKED FP32. All kernels ~50% VALUBusy with add-dominated scalar
// float math => VALU-issue bound (~35-50us floor at 1 op/inst). CDNA4 has
// full-rate packed fp32 (v_pk_add/mul/fma_f32, VOP3P). Complex values are
// now ext_vector_type(2) float: cadd/csub = 1 packed inst (was 2),
// cmul ~2-3 (was 4). Pure type change vs R10 (identical arithmetic,
// structure, schedule): R10 = K4 B=4 radix-{10,12,[9K9],12,10} in-place,
// R9 paired rows, R3 XCD swizzle.

#define PI2 6.2831853071795864f

typedef float v2f __attribute__((ext_vector_type(2)));

__device__ __forceinline__ v2f vmk(float x, float y){ v2f r; r.x = x; r.y = y; return r; }
__device__ __forceinline__ v2f cmul(v2f a, v2f b){
    return vmk(a.x, a.x)*b + vmk(-a.y, a.y)*vmk(b.y, b.x);
}
__device__ __forceinline__ float4 pk(v2f a, v2f b){ return make_float4(a.x,a.y,b.x,b.y); }

// b64 pad (h single-row path): +1 v2f per 16.
__device__ __forceinline__ int IDX(int a){ return a + (a >> 4); }
#define IDXSZ(n) ((n) + ((n) >> 4))
// K2 v2f pad: +2 per 32 (float4-aligned).
__device__ __forceinline__ int IDXP(int a){ return a + ((a >> 5) << 1); }
#define IDXPSZ(n) ((n) + (((n) >> 5) << 1) + 4)
// float4-slot pad: +1 slot per 16.
__device__ __forceinline__ int IDX4(int a){ return a + (a >> 4); }
#define IDX4SZ(n) ((n) + ((n) >> 4) + 2)

// K2 pair LDS (v2f buffer, float4 access).
__device__ __forceinline__ void ldp(const v2f* __restrict__ b, int pos,
                                    v2f& v0, v2f& v1){
    const float4 t = *(const float4*)&b[IDXP(2*pos)];
    v0 = vmk(t.x,t.y); v1 = vmk(t.z,t.w);
}
__device__ __forceinline__ void stp(v2f* __restrict__ b, int pos,
                                    v2f v0, v2f v1){
    *(float4*)&b[IDXP(2*pos)] = pk(v0, v1);
}
// Row-pair LDS (float4 buffer).
__device__ __forceinline__ void ld4(const float4* __restrict__ b, int pos,
                                    v2f& v0, v2f& v1){
    const float4 t = b[IDX4(pos)];
    v0 = vmk(t.x,t.y); v1 = vmk(t.z,t.w);
}
__device__ __forceinline__ void st4(float4* __restrict__ b, int pos,
                                    v2f v0, v2f v1){
    b[IDX4(pos)] = pk(v0, v1);
}
// K4 B=4 LDS: slot = 2*pos + g (g = pair group 0/1).
__device__ __forceinline__ void ld4g(const float4* __restrict__ b, int pos, int g,
                                     v2f& v0, v2f& v1){
    const float4 t = b[IDX4(2*pos+g)];
    v0 = vmk(t.x,t.y); v1 = vmk(t.z,t.w);
}
__device__ __forceinline__ void st4g(float4* __restrict__ b, int pos, int g,
                                     v2f v0, v2f v1){
    b[IDX4(2*pos+g)] = pk(v0, v1);
}

template<int DIR>
__device__ __forceinline__ void dft3(v2f x0, v2f x1, v2f x2,
                                     v2f& y0, v2f& y1, v2f& y2)
{
    constexpr float s3 = (float)DIR * 0.8660254037844386f;
    v2f t = x1 + x2, u = x1 - x2;
    v2f m = x0 - 0.5f*t;
    v2f iu = vmk(-s3*u.y, s3*u.x);
    y0 = x0 + t; y1 = m + iu; y2 = m - iu;
}

template<int DIR>
__device__ __forceinline__ void dft4(v2f a0, v2f a1, v2f a2, v2f a3,
                                     v2f& b0, v2f& b1, v2f& b2, v2f& b3)
{
    v2f t0 = a0+a2, t1 = a0-a2, t2 = a1+a3, t3 = a1-a3;
    v2f j3 = vmk(-(float)DIR*t3.y, (float)DIR*t3.x);
    b0 = t0+t2; b2 = t0-t2; b1 = t1+j3; b3 = t1-j3;
}

template<int DIR>
__device__ __forceinline__ void dft6(const v2f a[6], v2f b[6])
{
    v2f e0,e1,e2,o0,o1,o2;
    dft3<DIR>(a[0],a[2],a[4], e0,e1,e2);
    dft3<DIR>(a[1],a[3],a[5], o0,o1,o2);
    constexpr float s3 = (float)DIR * 0.8660254037844386f;
    const v2f w1 = vmk( 0.5f, s3);
    const v2f w2 = vmk(-0.5f, s3);
    v2f t1 = cmul(w1,o1), t2 = cmul(w2,o2);
    b[0]=e0+o0; b[3]=e0-o0;
    b[1]=e1+t1; b[4]=e1-t1;
    b[2]=e2+t2; b[5]=e2-t2;
}

template<int DIR>
__device__ __forceinline__ void dft8(const v2f a[8], v2f b[8])
{
    v2f e0,e1,e2,e3,o0,o1,o2,o3;
    dft4<DIR>(a[0],a[2],a[4],a[6], e0,e1,e2,e3);
    dft4<DIR>(a[1],a[3],a[5],a[7], o0,o1,o2,o3);
    constexpr float c = 0.70710678118654752f;
    const v2f w1 = vmk( c, (float)DIR*c);
    const v2f w3 = vmk(-c, (float)DIR*c);
    v2f t1 = cmul(w1,o1);
    v2f t2 = vmk(-(float)DIR*o2.y, (float)DIR*o2.x);
    v2f t3 = cmul(w3,o3);
    b[0]=e0+o0; b[4]=e0-o0;
    b[1]=e1+t1; b[5]=e1-t1;
    b[2]=e2+t2; b[6]=e2-t2;
    b[3]=e3+t3; b[7]=e3-t3;
}

template<int DIR>
__device__ __forceinline__ void dft5(const v2f a[5], v2f b[5])
{
    constexpr float C1 = 0.30901699437494742f, S1c = 0.9510565162951535f;
    constexpr float C2 = -0.8090169943749475f, S2c = 0.5877852522924731f;
    v2f t1 = a[1]+a[4], t2 = a[2]+a[3], d1 = a[1]-a[4], d2 = a[2]-a[3];
    v2f m1 = a[0] + C1*t1 + C2*t2;
    v2f m2 = a[0] + C2*t1 + C1*t2;
    v2f e1 = S1c*d1 + S2c*d2;
    v2f e2 = S2c*d1 - S1c*d2;
    v2f ie1 = vmk(-(float)DIR*e1.y, (float)DIR*e1.x);
    v2f ie2 = vmk(-(float)DIR*e2.y, (float)DIR*e2.x);
    b[0] = a[0] + t1 + t2;
    b[1] = m1+ie1; b[4] = m1-ie1;
    b[2] = m2+ie2; b[3] = m2-ie2;
}

// dft9 / dft10 / dft12 (structure verified R6/R10).
template<int DIR>
__device__ __forceinline__ void dft9(const v2f a[9], v2f b[9])
{
    v2f C0[3], C1[3], C2[3];
    dft3<DIR>(a[0],a[3],a[6], C0[0],C0[1],C0[2]);
    dft3<DIR>(a[1],a[4],a[7], C1[0],C1[1],C1[2]);
    dft3<DIR>(a[2],a[5],a[8], C2[0],C2[1],C2[2]);
    const v2f w91 = vmk(0.7660444431189780f, (float)DIR*0.6427876096865393f);
    const v2f w92 = vmk(0.1736481776669304f, (float)DIR*0.9848077530122081f);
    const v2f w94 = vmk(-0.9396926207859084f, (float)DIR*0.3420201433256687f);
    C1[1]=cmul(C1[1],w91); C1[2]=cmul(C1[2],w92);
    C2[1]=cmul(C2[1],w92); C2[2]=cmul(C2[2],w94);
    dft3<DIR>(C0[0],C1[0],C2[0], b[0],b[3],b[6]);
    dft3<DIR>(C0[1],C1[1],C2[1], b[1],b[4],b[7]);
    dft3<DIR>(C0[2],C1[2],C2[2], b[2],b[5],b[8]);
}

template<int DIR>
__device__ __forceinline__ void dft10(const v2f a[10], v2f b[10])
{
    v2f ae[5] = {a[0],a[2],a[4],a[6],a[8]};
    v2f ao[5] = {a[1],a[3],a[5],a[7],a[9]};
    v2f E[5], O[5];
    dft5<DIR>(ae, E); dft5<DIR>(ao, O);
    const v2f w1 = vmk( 0.8090169943749475f, (float)DIR*0.5877852522924731f);
    const v2f w2 = vmk( 0.3090169943749474f, (float)DIR*0.9510565162951535f);
    const v2f w3 = vmk(-0.3090169943749474f, (float)DIR*0.9510565162951535f);
    const v2f w4 = vmk(-0.8090169943749475f, (float)DIR*0.5877852522924731f);
    v2f t1 = cmul(O[1],w1), t2 = cmul(O[2],w2), t3 = cmul(O[3],w3), t4 = cmul(O[4],w4);
    b[0]=E[0]+O[0]; b[5]=E[0]-O[0];
    b[1]=E[1]+t1;   b[6]=E[1]-t1;
    b[2]=E[2]+t2;   b[7]=E[2]-t2;
    b[3]=E[3]+t3;   b[8]=E[3]-t3;
    b[4]=E[4]+t4;   b[9]=E[4]-t4;
}

template<int DIR>
__device__ __forceinline__ void dft12(const v2f a[12], v2f b[12])
{
    v2f C0[4], C1[4], C2[4];
    dft4<DIR>(a[0],a[3],a[6],a[9],  C0[0],C0[1],C0[2],C0[3]);
    dft4<DIR>(a[1],a[4],a[7],a[10], C1[0],C1[1],C1[2],C1[3]);
    dft4<DIR>(a[2],a[5],a[8],a[11], C2[0],C2[1],C2[2],C2[3]);
    const v2f w121 = vmk(0.8660254037844386f, (float)DIR*0.5f);
    const v2f w122 = vmk(0.5f, (float)DIR*0.8660254037844386f);
    const v2f w124 = vmk(-0.5f, (float)DIR*0.8660254037844386f);
    C1[1]=cmul(C1[1],w121); C1[2]=cmul(C1[2],w122);
    C1[3]=vmk(-(float)DIR*C1[3].y, (float)DIR*C1[3].x);
    C2[1]=cmul(C2[1],w122); C2[2]=cmul(C2[2],w124);
    C2[3]=-C2[3];
    dft3<DIR>(C0[0],C1[0],C2[0], b[0],b[4],b[8]);
    dft3<DIR>(C0[1],C1[1],C2[1], b[1],b[5],b[9]);
    dft3<DIR>(C0[2],C1[2],C2[2], b[2],b[6],b[10]);
    dft3<DIR>(C0[3],C1[3],C2[3], b[3],b[7],b[11]);
}

// ============ h single-row path (b64, dbuf) ============

__device__ __forceinline__ void row_s1_fwd_h(const float* __restrict__ xa,
                                             v2f* __restrict__ bA, int tid)
{
    constexpr float STEP = -PI2 / 1920.0f;
    const v2f z = vmk(0.f,0.f);
    for (int p = tid; p < 240; p += 256) {
        v2f a[8], b[8];
        a[0]=z; a[1]=z; a[6]=z; a[7]=z;
        a[2] = vmk(xa[p],     0.f);
        a[3] = vmk(xa[p+240], 0.f);
        a[4] = vmk(xa[p+480], 0.f);
        a[5] = vmk(xa[p+720], 0.f);
        dft8<-1>(a,b);
        float sv, cv; __sincosf(STEP * (float)p, &sv, &cv);
        v2f w1 = vmk(cv, sv), w = w1;
        b[1] = cmul(b[1], w);
        #pragma unroll
        for (int u = 2; u < 8; ++u) { w = cmul(w, w1); b[u] = cmul(b[u], w); }
        #pragma unroll
        for (int u = 0; u < 8; ++u) bA[IDX(8*p + u)] = b[u];
    }
}

template<int DIR, int R, int NCUR, int S>
__device__ __forceinline__ void mid_stage(const v2f* __restrict__ src,
                                          v2f* __restrict__ dst, int tid)
{
    constexpr int M  = NCUR / R;
    constexpr int NB = M * S;
    constexpr float STEP = (float)DIR * PI2 / (float)NCUR;
    for (int i = tid; i < NB; i += 256) {
        const int p = i / S;
        v2f a[R], b[R];
        #pragma unroll
        for (int t = 0; t < R; ++t) a[t] = src[IDX(i + S*M*t)];
        if constexpr (R == 6) dft6<DIR>(a,b); else dft8<DIR>(a,b);
        float sv, cv; __sincosf(STEP * (float)p, &sv, &cv);
        v2f w1 = vmk(cv, sv), w = w1;
        b[1] = cmul(b[1], w);
        #pragma unroll
        for (int u = 2; u < R; ++u) { w = cmul(w, w1); b[u] = cmul(b[u], w); }
        const int ob = (i - p*S) + S*(R*p);
        #pragma unroll
        for (int u = 0; u < R; ++u) dst[IDX(ob + S*u)] = b[u];
    }
}

__device__ __forceinline__ void row_fin5_store_h(const v2f* __restrict__ src,
                                                 v2f* __restrict__ gdst, int tid)
{
    for (int q = tid; q < 384; q += 256) {
        v2f a[5], b[5];
        #pragma unroll
        for (int u = 0; u < 5; ++u) a[u] = src[IDX(q + 384*u)];
        dft5<-1>(a,b);
        #pragma unroll
        for (int u = 0; u < 5; ++u) gdst[q + 384*u] = b[u];
    }
}

// ============ row-pair path (float4, in-place) ============

__device__ __forceinline__ void rp_s1_fwd(const float* __restrict__ xa,
                                          const float* __restrict__ xb,
                                          float4* __restrict__ sb, int tid)
{
    constexpr float STEP = -PI2 / 1920.0f;
    const v2f z = vmk(0.f,0.f);
    for (int p = tid; p < 240; p += 256) {
        v2f a0[8], a1[8], b0[8], b1[8];
        a0[0]=a0[1]=a0[6]=a0[7]=z; a1[0]=a1[1]=a1[6]=a1[7]=z;
        #pragma unroll
        for (int t = 0; t < 4; ++t) {
            a0[2+t] = vmk(xa[p+240*t],     xb[p+240*t]);
            a1[2+t] = vmk(xa[960+p+240*t], xb[960+p+240*t]);
        }
        dft8<-1>(a0,b0); dft8<-1>(a1,b1);
        float sv, cv; __sincosf(STEP*(float)p, &sv, &cv);
        v2f w1 = vmk(cv,sv), w = w1;
        b0[1]=cmul(b0[1],w); b1[1]=cmul(b1[1],w);
        #pragma unroll
        for (int u = 2; u < 8; ++u){ w = cmul(w,w1); b0[u]=cmul(b0[u],w); b1[u]=cmul(b1[u],w); }
        #pragma unroll
        for (int u = 0; u < 8; ++u) st4(sb, 8*p+u, b0[u], b1[u]);
    }
}

__device__ __forceinline__ void rp_s1_inv(const v2f* __restrict__ Zr0,
                                          const v2f* __restrict__ Zr1,
                                          float4* __restrict__ sb, int tid)
{
    constexpr float STEP = PI2 / 1920.0f;
    for (int p = tid; p < 240; p += 256) {
        v2f a0[8], a1[8], b0[8], b1[8];
        #pragma unroll
        for (int t = 0; t < 8; ++t) { a0[t] = Zr0[p+240*t]; a1[t] = Zr1[p+240*t]; }
        dft8<1>(a0,b0); dft8<1>(a1,b1);
        float sv, cv; __sincosf(STEP*(float)p, &sv, &cv);
        v2f w1 = vmk(cv,sv), w = w1;
        b0[1]=cmul(b0[1],w); b1[1]=cmul(b1[1],w);
        #pragma unroll
        for (int u = 2; u < 8; ++u){ w = cmul(w,w1); b0[u]=cmul(b0[u],w); b1[u]=cmul(b1[u],w); }
        #pragma unroll
        for (int u = 0; u < 8; ++u) st4(sb, 8*p+u, b0[u], b1[u]);
    }
}

template<int DIR>
__device__ __forceinline__ void rp_mid8_ip(float4* __restrict__ sb, int tid)
{
    constexpr float STEP = (float)DIR * PI2 / 240.0f;
    const bool act = tid < 240;
    v2f b0[8], b1[8]; int ob = 0;
    if (act) {
        const int p = tid >> 3;
        v2f a0[8], a1[8];
        #pragma unroll
        for (int t = 0; t < 8; ++t) ld4(sb, tid + 240*t, a0[t], a1[t]);
        dft8<DIR>(a0,b0); dft8<DIR>(a1,b1);
        float sv, cv; __sincosf(STEP*(float)p, &sv, &cv);
        v2f w1 = vmk(cv,sv), w = w1;
        b0[1]=cmul(b0[1],w); b1[1]=cmul(b1[1],w);
        #pragma unroll
        for (int u = 2; u < 8; ++u){ w = cmul(w,w1); b0[u]=cmul(b0[u],w); b1[u]=cmul(b1[u],w); }
        ob = (tid - 8*p) + 64*p;
    }
    __syncthreads();
    if (act) {
        #pragma unroll
        for (int u = 0; u < 8; ++u) st4(sb, ob + 8*u, b0[u], b1[u]);
    }
    __syncthreads();
}

template<int DIR>
__device__ __forceinline__ void rp_mid6_ip(float4* __restrict__ sb, int tid)
{
    constexpr float STEP = (float)DIR * PI2 / 30.0f;
    v2f c0[6], c1[6], d0[6], d1[6]; int ob0, ob1 = 0;
    {
        const int i = tid, p = i >> 6;
        v2f a0[6], a1[6];
        #pragma unroll
        for (int t = 0; t < 6; ++t) ld4(sb, i + 320*t, a0[t], a1[t]);
        dft6<DIR>(a0,c0); dft6<DIR>(a1,c1);
        float sv, cv; __sincosf(STEP*(float)p, &sv, &cv);
        v2f w1 = vmk(cv,sv), w = w1;
        c0[1]=cmul(c0[1],w); c1[1]=cmul(c1[1],w);
        #pragma unroll
        for (int u = 2; u < 6; ++u){ w = cmul(w,w1); c0[u]=cmul(c0[u],w); c1[u]=cmul(c1[u],w); }
        ob0 = (i - 64*p) + 384*p;
    }
    const bool act2 = tid < 64;
    if (act2) {
        const int i = 256 + tid;                 // p = 4
        v2f a0[6], a1[6];
        #pragma unroll
        for (int t = 0; t < 6; ++t) ld4(sb, i + 320*t, a0[t], a1[t]);
        dft6<DIR>(a0,d0); dft6<DIR>(a1,d1);
        float sv, cv; __sincosf(STEP*4.0f, &sv, &cv);
        v2f w1 = vmk(cv,sv), w = w1;
        d0[1]=cmul(d0[1],w); d1[1]=cmul(d1[1],w);
        #pragma unroll
        for (int u = 2; u < 6; ++u){ w = cmul(w,w1); d0[u]=cmul(d0[u],w); d1[u]=cmul(d1[u],w); }
        ob1 = tid + 1536;
    }
    __syncthreads();
    {
        #pragma unroll
        for (int u = 0; u < 6; ++u) st4(sb, ob0 + 64*u, c0[u], c1[u]);
    }
    if (act2) {
        #pragma unroll
        for (int u = 0; u < 6; ++u) st4(sb, ob1 + 64*u, d0[u], d1[u]);
    }
    __syncthreads();
}

__device__ __forceinline__ void rp_fin5_storeZ(const float4* __restrict__ sb,
                                               v2f* __restrict__ Zr0,
                                               v2f* __restrict__ Zr1, int tid)
{
    for (int q = tid; q < 384; q += 256) {
        v2f a0[5],a1[5],b0[5],b1[5];
        #pragma unroll
        for (int u = 0; u < 5; ++u) ld4(sb, q + 384*u, a0[u], a1[u]);
        dft5<-1>(a0,b0); dft5<-1>(a1,b1);
        #pragma unroll
        for (int u = 0; u < 5; ++u) { Zr0[q+384*u] = b0[u]; Zr1[q+384*u] = b1[u]; }
    }
}

__device__ __forceinline__ void rp_fin5_crop(const float4* __restrict__ sb,
                                             float* __restrict__ oa0, float* __restrict__ ob0,
                                             float* __restrict__ oa1, float* __restrict__ ob1,
                                             int tid)
{
    for (int q = tid; q < 384; q += 256) {
        v2f a0[5],a1[5],b0[5],b1[5];
        #pragma unroll
        for (int u = 0; u < 5; ++u) ld4(sb, q + 384*u, a0[u], a1[u]);
        dft5<1>(a0,b0); dft5<1>(a1,b1);
        oa0[q+480] = b0[0].x; ob0[q+480] = b0[0].y;
        oa1[q+480] = b1[0].x; ob1[q+480] = b1[0].y;
        if (q < 96)   { oa0[q+864] = b0[1].x; ob0[q+864] = b0[1].y;
                        oa1[q+864] = b1[1].x; ob1[q+864] = b1[1].y; }
        if (q >= 288) { oa0[q-288] = b0[3].x; ob0[q-288] = b0[3].y;
                        oa1[q-288] = b1[3].x; ob1[q-288] = b1[3].y; }
        oa0[q+96]  = b0[4].x; ob0[q+96]  = b0[4].y;
        oa1[q+96]  = b1[4].x; ob1[q+96]  = b1[4].y;
    }
}

// ============ K2 column path (sincos, pair-per-thread, dbuf) ============

__device__ __forceinline__ void col_s1_fwd_pair(const v2f* __restrict__ g, int c0,
                                                v2f* __restrict__ bA, int tid)
{
    constexpr float STEP = -PI2 / 1080.0f;
    const v2f z = vmk(0.f,0.f);
    const float4* gc = (const float4*)(g + c0);
    for (int p = tid; p < 180; p += 256) {
        v2f a0[6], a1[6], b0[6], b1[6];
        a0[0]=a0[5]=a1[0]=a1[5]=z;
        if (p >= 90) { float4 t = gc[(p-90)*960]; a0[1]=vmk(t.x,t.y); a1[1]=vmk(t.z,t.w); }
        else         { a0[1]=a1[1]=z; }
        { float4 t = gc[(p+90)*960];  a0[2]=vmk(t.x,t.y); a1[2]=vmk(t.z,t.w); }
        { float4 t = gc[(p+270)*960]; a0[3]=vmk(t.x,t.y); a1[3]=vmk(t.z,t.w); }
        if (p < 90)  { float4 t = gc[(p+450)*960]; a0[4]=vmk(t.x,t.y); a1[4]=vmk(t.z,t.w); }
        else         { a0[4]=a1[4]=z; }
        dft6<-1>(a0,b0); dft6<-1>(a1,b1);
        float sv, cv; __sincosf(STEP*(float)p, &sv, &cv);
        v2f w1 = vmk(cv,sv), w = w1;
        b0[1]=cmul(b0[1],w); b1[1]=cmul(b1[1],w);
        #pragma unroll
        for (int u = 2; u < 6; ++u){ w = cmul(w,w1); b0[u]=cmul(b0[u],w); b1[u]=cmul(b1[u],w); }
        #pragma unroll
        for (int u = 0; u < 6; ++u) stp(bA, 6*p + u, b0[u], b1[u]);
    }
}

template<int DIR, int NCUR, int SC>
__device__ __forceinline__ void mid_pair(const v2f* __restrict__ src,
                                         v2f* __restrict__ dst, int tid)
{
    constexpr int NB = 180;
    constexpr float STEP = (float)DIR * PI2 / (float)NCUR;
    for (int ic = tid; ic < NB; ic += 256) {
        const int p = ic / SC;
        v2f a0[6], a1[6], b0[6], b1[6];
        #pragma unroll
        for (int t = 0; t < 6; ++t) ldp(src, ic + NB*t, a0[t], a1[t]);
        dft6<DIR>(a0,b0); dft6<DIR>(a1,b1);
        float sv, cv; __sincosf(STEP*(float)p, &sv, &cv);
        v2f w1 = vmk(cv,sv), w = w1;
        b0[1]=cmul(b0[1],w); b1[1]=cmul(b1[1],w);
        #pragma unroll
        for (int u = 2; u < 6; ++u){ w = cmul(w,w1); b0[u]=cmul(b0[u],w); b1[u]=cmul(b1[u],w); }
        const int ob = (ic - p*SC) + SC*6*p;
        #pragma unroll
        for (int u = 0; u < 6; ++u) stp(dst, ob + SC*u, b0[u], b1[u]);
    }
}

// ============ K4 B=4 high-radix in-place pieces ============

__device__ __forceinline__ void c4_s1_fwd10(const v2f* __restrict__ Zp, int c0,
                                            float4* __restrict__ sb, int tid)
{
    constexpr float STEP = -PI2 / 1080.0f;
    const v2f z = vmk(0.f,0.f);
    const float4* gc = (const float4*)(Zp + c0);
    const bool act = tid < 216;
    if (act) {
        const int g = tid & 1, p = tid >> 1;
        v2f a0[10], a1[10], b0[10], b1[10];
        a0[0]=a0[1]=a0[8]=a0[9]=z; a1[0]=a1[1]=a1[8]=a1[9]=z;
        if (p >= 54) { float4 t = gc[(p-54)*960+g]; a0[2]=vmk(t.x,t.y); a1[2]=vmk(t.z,t.w); }
        else         { a0[2]=a1[2]=z; }
        { float4 t = gc[(p+54)*960+g];  a0[3]=vmk(t.x,t.y); a1[3]=vmk(t.z,t.w); }
        { float4 t = gc[(p+162)*960+g]; a0[4]=vmk(t.x,t.y); a1[4]=vmk(t.z,t.w); }
        { float4 t = gc[(p+270)*960+g]; a0[5]=vmk(t.x,t.y); a1[5]=vmk(t.z,t.w); }
        { float4 t = gc[(p+378)*960+g]; a0[6]=vmk(t.x,t.y); a1[6]=vmk(t.z,t.w); }
        if (p < 54)  { float4 t = gc[(p+486)*960+g]; a0[7]=vmk(t.x,t.y); a1[7]=vmk(t.z,t.w); }
        else         { a0[7]=a1[7]=z; }
        dft10<-1>(a0,b0); dft10<-1>(a1,b1);
        float sv, cv; __sincosf(STEP*(float)p, &sv, &cv);
        v2f w1 = vmk(cv,sv), w = w1;
        b0[1]=cmul(b0[1],w); b1[1]=cmul(b1[1],w);
        #pragma unroll
        for (int u = 2; u < 10; ++u){ w = cmul(w,w1); b0[u]=cmul(b0[u],w); b1[u]=cmul(b1[u],w); }
        #pragma unroll
        for (int u = 0; u < 10; ++u) st4g(sb, 10*p+u, g, b0[u], b1[u]);
    }
    __syncthreads();
}

template<int DIR, int NCUR, int SC>
__device__ __forceinline__ void c4_mid12_ip(float4* __restrict__ sb, int tid)
{
    constexpr int NB = (NCUR/12)*SC;   // 90
    constexpr float STEP = (float)DIR * PI2 / (float)NCUR;
    const bool act = tid < 2*NB;
    v2f b0[12], b1[12]; int ob = 0, g = 0;
    if (act) {
        g = tid & 1;
        const int ic = tid >> 1;
        const int p = ic / SC;
        v2f a0[12], a1[12];
        #pragma unroll
        for (int t = 0; t < 12; ++t) ld4g(sb, ic + NB*t, g, a0[t], a1[t]);
        dft12<DIR>(a0,b0); dft12<DIR>(a1,b1);
        float sv, cv; __sincosf(STEP*(float)p, &sv, &cv);
        v2f w1 = vmk(cv,sv), w = w1;
        b0[1]=cmul(b0[1],w); b1[1]=cmul(b1[1],w);
        #pragma unroll
        for (int u = 2; u < 12; ++u){ w = cmul(w,w1); b0[u]=cmul(b0[u],w); b1[u]=cmul(b1[u],w); }
        ob = (ic - p*SC) + SC*12*p;
    }
    __syncthreads();
    if (act) {
        #pragma unroll
        for (int u = 0; u < 12; ++u) st4g(sb, ob + SC*u, g, b0[u], b1[u]);
    }
    __syncthreads();
}

__device__ __forceinline__ void c4_f9K9_ip(float4* __restrict__ sb,
                                           const float4* __restrict__ KI,
                                           int cg, int tid)
{
    constexpr float STEP = PI2 / 1080.0f;
    const bool act = tid < 240;
    v2f d0[9], d1[9]; int q = 0, g = 0;
    if (act) {
        g = tid & 1; q = tid >> 1;
        const float4* Kc = KI + (cg*2 + g)*1080;
        v2f a0[9], a1[9], s0[9], s1[9];
        #pragma unroll
        for (int u = 0; u < 9; ++u) ld4g(sb, q + 120*u, g, a0[u], a1[u]);
        dft9<-1>(a0,s0); dft9<-1>(a1,s1);
        #pragma unroll
        for (int u = 0; u < 9; ++u) {
            float4 kk = Kc[q + 120*u];
            s0[u] = cmul(s0[u], vmk(kk.x,kk.y));
            s1[u] = cmul(s1[u], vmk(kk.z,kk.w));
        }
        dft9<1>(s0,d0); dft9<1>(s1,d1);
        float sv, cv; __sincosf(STEP*(float)q, &sv, &cv);
        v2f w1 = vmk(cv,sv), w = w1;
        d0[1]=cmul(d0[1],w); d1[1]=cmul(d1[1],w);
        #pragma unroll
        for (int u = 2; u < 9; ++u){ w = cmul(w,w1); d0[u]=cmul(d0[u],w); d1[u]=cmul(d1[u],w); }
    }
    __syncthreads();
    if (act) {
        #pragma unroll
        for (int u = 0; u < 9; ++u) st4g(sb, 9*q + u, g, d0[u], d1[u]);
    }
    __syncthreads();
}

__device__ __forceinline__ void c4_fin10_crop(const float4* __restrict__ sb,
                                              v2f* __restrict__ Zp,
                                              int c0, int tid)
{
    const bool act = tid < 216;
    if (!act) return;
    const int g = tid & 1, q = tid >> 1;
    float4* gc = (float4*)(Zp + c0);
    v2f a0[10], a1[10], b0[10], b1[10];
    #pragma unroll
    for (int u = 0; u < 10; ++u) ld4g(sb, q + 108*u, g, a0[u], a1[u]);
    dft10<1>(a0,b0); dft10<1>(a1,b1);
    gc[(q+270)*960+g] = pk(b0[0], b1[0]);
    gc[(q+378)*960+g] = pk(b0[1], b1[1]);
    if (q < 54)  gc[(q+486)*960+g] = pk(b0[2], b1[2]);
    if (q >= 54) gc[(q-54)*960+g]  = pk(b0[7], b1[7]);
    gc[(q+54)*960+g]  = pk(b0[8], b1[8]);
    gc[(q+162)*960+g] = pk(b0[9], b1[9]);
}

// ============ kernels ============

// K13: row forward FFTs. Blocks [0,1080): x pairs; [1080,1620): h rows.
__global__ __launch_bounds__(256,5) void k_row_fwd(const float* __restrict__ x,
                                                   const float* __restrict__ h,
                                                   v2f* __restrict__ Z,
                                                   v2f* __restrict__ Hrow)
{
    __shared__ float4 sb[IDX4SZ(1920)];
    const int tid = threadIdx.x;
    if (blockIdx.x < 1080) {
        const int pp = blockIdx.x / 270;
        const int r0 = (blockIdx.x % 270) * 2;
        const float* xa = x + ((2*pp  )*540 + r0)*960;
        const float* xb = x + ((2*pp+1)*540 + r0)*960;
        rp_s1_fwd(xa, xb, sb, tid); __syncthreads();
        rp_mid8_ip<-1>(sb, tid);
        rp_mid6_ip<-1>(sb, tid);
        v2f* Zr0 = Z + (pp*540 + r0)*1920;
        rp_fin5_storeZ(sb, Zr0, Zr0 + 1920, tid);
    } else {
        v2f* bA = (v2f*)sb;
        v2f* bB = bA + IDXSZ(1920);
        const int r = blockIdx.x - 1080;
        row_s1_fwd_h(h + r*960, bA, tid); __syncthreads();
        mid_stage<-1,8,240, 8>(bA, bB, tid); __syncthreads();
        mid_stage<-1,6, 30,64>(bB, bA, tid); __syncthreads();
        row_fin5_store_h(bA, Hrow + r*1920, tid);
    }
}

// K2: column FFTs of Hrow (pair/thread, dbuf) + build pair-interleaved KI.
__global__ __launch_bounds__(256,4) void k_col_fft_h_buildK(const v2f* __restrict__ Hrow,
                                                            const float* __restrict__ mu1,
                                                            float4* __restrict__ KI)
{
    __shared__ v2f bA[IDXPSZ(2160)], bB[IDXPSZ(2160)];
    const int tid = threadIdx.x;
    const int xcd = blockIdx.x & 7, idx = blockIdx.x >> 3;
    const int cpair = xcd*120 + idx, c0 = cpair*2;
    col_s1_fwd_pair(Hrow, c0, bA, tid);  __syncthreads();
    mid_pair<-1,180, 6>(bA, bB, tid);    __syncthreads();
    mid_pair<-1, 30,36>(bB, bA, tid);    __syncthreads();
    const float sc = mu1[4] / ((1.0f + 1e-6f) * 2073600.0f);
    const float cos0 = __cosf(PI2 * (float)(c0  ) * (1.0f/1920.0f));
    const float cos1 = __cosf(PI2 * (float)(c0+1) * (1.0f/1920.0f));
    float4* Kc = KI + cpair*1080;
    for (int p = tid; p < 216; p += 256) {
        v2f a0[5],a1[5],b0[5],b1[5];
        #pragma unroll
        for (int u = 0; u < 5; ++u) ldp(bA, p + 216*u, a0[u], a1[u]);
        dft5<-1>(a0,b0); dft5<-1>(a1,b1);
        #pragma unroll
        for (int u = 0; u < 5; ++u) {
            const int k = p + 216*u;
            const float cosk = __cosf(PI2 * (float)k * (1.0f/1080.0f));
            float m0 = b0[u].x*b0[u].x + b0[u].y*b0[u].y;
            float m1 = b1[u].x*b1[u].x + b1[u].y*b1[u].y;
            float f0 = sc / (1e-6f*m0 + 1e-5f*(4.0f - 2.0f*cosk - 2.0f*cos0) + 4e-5f);
            float f1 = sc / (1e-6f*m1 + 1e-5f*(4.0f - 2.0f*cosk - 2.0f*cos1) + 4e-5f);
            Kc[k] = make_float4(f0*b0[u].x, -f0*b0[u].y, f1*b1[u].x, -f1*b1[u].y);
        }
    }
}

// K4: B=4 columns/block, radix {10,12,[9 K 9],12,10}, IN-PLACE (36.7KB LDS,
// 4 blocks/CU). 5 passes / 7 barriers. Grid 1920; XCD swizzle.
__global__ __launch_bounds__(256,4) void k_col_fused(v2f* __restrict__ Z,
                                                     const float4* __restrict__ KI)
{
    __shared__ float4 sb[IDX4SZ(2160)];
    const int tid = threadIdx.x;
    const int xcd = blockIdx.x & 7, idx = blockIdx.x >> 3;   // idx in [0,240)
    const int pp  = idx / 60;
    const int cg  = xcd*60 + (idx - pp*60);                  // col-group [0,480)
    const int c0  = cg*4;
    v2f* Zp = Z + pp*540*1920;
    c4_s1_fwd10(Zp, c0, sb, tid);
    c4_mid12_ip<-1,108,10>(sb, tid);
    c4_f9K9_ip(sb, KI, cg, tid);
    c4_mid12_ip< 1,120, 9>(sb, tid);
    c4_fin10_crop(sb, Zp, c0, tid);
}

// K5: row inverse FFTs, paired rows + crop + split into real outputs.
__global__ __launch_bounds__(256,5) void k_row_inv_out(const v2f* __restrict__ Z,
                                                       float* __restrict__ out)
{
    __shared__ float4 sb[IDX4SZ(1920)];
    const int tid = threadIdx.x;
    const int pp = blockIdx.x / 270;
    const int r0 = (blockIdx.x % 270) * 2;
    const v2f* Zr0 = Z + (pp*540 + r0)*1920;
    rp_s1_inv(Zr0, Zr0 + 1920, sb, tid); __syncthreads();
    rp_mid8_ip<1>(sb, tid);
    rp_mid6_ip<1>(sb, tid);
    float* oa0 = out + ((2*pp  )*540 + r0)*960;
    float* ob0 = out + ((2*pp+1)*540 + r0)*960;
    rp_fin5_crop(sb, oa0, ob0, oa0 + 960, ob0 + 960, tid);
}

extern "C" void kernel_launch(void* const* d_in, const int* in_sizes, int n_in,
                              void* d_out, int out_size, void* d_ws, size_t ws_size,
                              hipStream_t stream)
{
    (void)in_sizes; (void)n_in; (void)out_size; (void)ws_size;
    const float* x   = (const float*)d_in[0];
    const float* h   = (const float*)d_in[1];
    const float* mu1 = (const float*)d_in[2];
    float*       out = (float*)d_out;

    // ws layout: KI (960*1080 f4 = 16.6MB) | Z (4*540*1920 v2f = 33.2MB) |
    // Hrow (540*1920 v2f = 8.3MB).
    float4* KI   = (float4*)d_ws;
    v2f*    Z    = (v2f*)(KI + 960*1080);
    v2f*    Hrow = Z + 4*540*1920;

    k_row_fwd         <<<1620,   256, 0, stream>>>(x, h, Z, Hrow);
    k_col_fft_h_buildK<<<960,    256, 0, stream>>>(Hrow, mu1, KI);
    k_col_fused       <<<1920,   256, 0, stream>>>(Z, KI);
    k_row_inv_out     <<<1080,   256, 0, stream>>>(Z, out);
}